// Round 8
// baseline (1808.545 us; speedup 1.0000x reference)
//
#include <hip/hip_runtime.h>
#include <hip/hip_bf16.h>
#include <stdint.h>

#define D_ 128
#define R_ 200
#define B_ 50
#define N_ 100000
#define TE 64
#define G_ 8
#define RG_ 4
#define MAXC 8

typedef __attribute__((ext_vector_type(8))) short s8b;
typedef __attribute__((ext_vector_type(4))) float f32x4;
typedef __attribute__((ext_vector_type(4))) uint u32x4;

// ---------------- helpers ----------------

__device__ __forceinline__ ushort f2bf(float f) {   // RTN-even fp32 -> bf16
  uint u = __float_as_uint(f);
  return (ushort)((u + 0x7fffu + ((u >> 16) & 1u)) >> 16);
}
__device__ __forceinline__ float bf2f(ushort u) {
  return __uint_as_float(((uint)u) << 16);
}

// ---------------- counting / sorting machinery ----------------

__global__ __launch_bounds__(256) void k_hist(const int* __restrict__ et, int E, int* __restrict__ hist) {
  __shared__ int h[R_];
  for (int i = threadIdx.x; i < R_; i += 256) h[i] = 0;
  __syncthreads();
  int base = blockIdx.x * 4096;
  for (int j = 0; j < 16; j++) {
    int i = base + j * 256 + threadIdx.x;
    if (i < E) atomicAdd(&h[et[i]], 1);
  }
  __syncthreads();
  for (int i = threadIdx.x; i < R_; i += 256) { int v = h[i]; if (v) atomicAdd(&hist[i], v); }
}

// parallel relation scan with TE-padding (1 block, 256 threads)
__global__ __launch_bounds__(256) void k_scanRel(const int* __restrict__ hist,
                                                 int* __restrict__ padOff, int* __restrict__ cursor) {
  __shared__ int s[256];
  int tid = threadIdx.x;
  int v = (tid < R_) ? ((hist[tid] + TE - 1) / TE) * TE : 0;
  s[tid] = v;
  __syncthreads();
  for (int off = 1; off < 256; off <<= 1) {
    int t = (tid >= off) ? s[tid - off] : 0;
    __syncthreads();
    s[tid] += t;
    __syncthreads();
  }
  if (tid < R_) { int e = s[tid] - v; padOff[tid] = e; cursor[tid] = e; }
  if (tid == R_ - 1) padOff[R_] = s[tid];
}

__global__ __launch_bounds__(256) void k_scatter(const int* __restrict__ src, const int* __restrict__ dst,
                                                 const int* __restrict__ et, int E,
                                                 int* __restrict__ cursor,
                                                 int* __restrict__ srcS, int* __restrict__ dstS) {
  __shared__ int h[R_];
  __shared__ int gb[R_];
  for (int i = threadIdx.x; i < R_; i += 256) h[i] = 0;
  __syncthreads();
  int base = blockIdx.x * 4096;
  int lrank[16];
#pragma unroll
  for (int j = 0; j < 16; j++) {
    int i = base + j * 256 + threadIdx.x;
    lrank[j] = (i < E) ? atomicAdd(&h[et[i]], 1) : 0;
  }
  __syncthreads();
  for (int i = threadIdx.x; i < R_; i += 256) { int v = h[i]; gb[i] = v ? atomicAdd(&cursor[i], v) : 0; }
  __syncthreads();
#pragma unroll
  for (int j = 0; j < 16; j++) {
    int i = base + j * 256 + threadIdx.x;
    if (i < E) {
      int r = et[i];
      int pos = gb[r] + lrank[j];
      srcS[pos] = src[i];
      dstS[pos] = dst[i];
    }
  }
}

__global__ __launch_bounds__(256) void k_tileRel(const int* __restrict__ padOff, int* __restrict__ tileRel, int uT) {
  int t = blockIdx.x * 256 + threadIdx.x;
  if (t >= uT) return;
  int base = t * TE;
  if (base >= padOff[R_]) { tileRel[t] = 0; return; }
  int lo = 0, hi = R_ - 1;
  while (lo < hi) { int mid = (lo + hi + 1) >> 1; if (padOff[mid] <= base) lo = mid; else hi = mid - 1; }
  tileRel[t] = lo;
}

// ---------------- dst-sort: parallel 3-kernel scan ----------------

__global__ __launch_bounds__(256) void k_countDst(const int* __restrict__ dst, int E, int* __restrict__ deg) {
  int i = blockIdx.x * 256 + threadIdx.x;
  if (i < E) atomicAdd(&deg[dst[i]], 1);
}

__global__ __launch_bounds__(256) void k_degPart(const int* __restrict__ deg, int* __restrict__ blkSum) {
  __shared__ int ws_[4];
  int i = blockIdx.x * 256 + threadIdx.x;
  int v = (i < N_) ? deg[i] : 0;
#pragma unroll
  for (int off = 32; off >= 1; off >>= 1) v += __shfl_down(v, off);
  if ((threadIdx.x & 63) == 0) ws_[threadIdx.x >> 6] = v;
  __syncthreads();
  if (threadIdx.x == 0) blkSum[blockIdx.x] = ws_[0] + ws_[1] + ws_[2] + ws_[3];
}

__global__ __launch_bounds__(512) void k_scanBlk(const int* __restrict__ blkSum, int* __restrict__ blkOff, int nblk) {
  __shared__ int s[512];
  int tid = threadIdx.x;
  int v = (tid < nblk) ? blkSum[tid] : 0;
  s[tid] = v;
  __syncthreads();
  for (int off = 1; off < 512; off <<= 1) {
    int t = (tid >= off) ? s[tid - off] : 0;
    __syncthreads();
    s[tid] += t;
    __syncthreads();
  }
  if (tid < nblk) blkOff[tid] = s[tid] - v;   // exclusive
}

__global__ __launch_bounds__(256) void k_writeOff(const int* __restrict__ deg, const int* __restrict__ blkOff,
                                                  int* __restrict__ dstOff, int* __restrict__ cur) {
  __shared__ int s[256];
  int i = blockIdx.x * 256 + threadIdx.x;
  int tid = threadIdx.x;
  int v = (i < N_) ? deg[i] : 0;
  s[tid] = v;
  __syncthreads();
  for (int off = 1; off < 256; off <<= 1) {
    int t = (tid >= off) ? s[tid - off] : 0;
    __syncthreads();
    s[tid] += t;
    __syncthreads();
  }
  int e = blkOff[blockIdx.x] + s[tid] - v;    // global exclusive prefix
  if (i < N_) { dstOff[i] = e; cur[i] = e; }
  else if (i == N_) dstOff[N_] = e;
}

__global__ __launch_bounds__(256) void k_scatterDst(const int* __restrict__ dstS,
                                                    const int* __restrict__ padOff, int* __restrict__ cur,
                                                    int* __restrict__ posbuf, int plo, int phi) {
  int p = plo + blockIdx.x * 256 + threadIdx.x;
  if (p >= phi || p >= padOff[R_]) return;
  int d = dstS[p];
  if (d < 0) return;                 // padding slot
  int j = atomicAdd(&cur[d], 1);
  posbuf[j] = p;
}

__global__ __launch_bounds__(256) void k_copyBound(const int* __restrict__ cur, int* __restrict__ bnd) {
  int d = blockIdx.x * 256 + threadIdx.x;
  if (d < N_) bnd[d] = cur[d];
}

// ---------------- per-edge mean-norm from dst-sorted segments ----------------

__global__ __launch_bounds__(256) void k_norm(const int* __restrict__ posbuf, const int* __restrict__ dstOff,
                                              const int* __restrict__ tileRel, float* __restrict__ normS) {
  __shared__ int rels[4][128];
  int d = blockIdx.x * 4 + (threadIdx.x >> 6);
  int sub = threadIdx.x >> 6;
  int l = threadIdx.x & 63;
  int s0 = 0, deg = 0;
  if (d < N_) { s0 = dstOff[d]; deg = dstOff[d + 1] - s0; }
  int cap = deg < 128 ? deg : 128;
  int myp[4]; int myr[4];
  for (int j = l, t = 0; j < cap; j += 64, ++t) {
    int p = posbuf[s0 + j];
    int r = tileRel[p >> 6];
    rels[sub][j] = r;
    if (t < 4) { myp[t] = p; myr[t] = r; }
  }
  __syncthreads();
  if (d >= N_) return;
  for (int j = l, t = 0; j < deg; j += 64, ++t) {
    int p, r;
    if (j < 128 && t < 4) { p = myp[t]; r = myr[t]; }
    else { p = posbuf[s0 + j]; r = tileRel[p >> 6]; }
    int cnt = 0;
    for (int k = 0; k < deg; k++) {
      int rk = (k < 128) ? rels[sub][k] : tileRel[posbuf[s0 + k] >> 6];
      cnt += (rk == r) ? 1 : 0;
    }
    normS[p] = 1.0f / (float)(cnt > 0 ? cnt : 1);
  }
}

// ---------------- W_r = sum_b comp[r,b]*basis[b]; pack to B-fragment order ----------------

__global__ __launch_bounds__(256) void k_computeW(const float* __restrict__ comp, const float* __restrict__ basis,
                                                  float* __restrict__ W) {
  __shared__ float c[B_];
  int r = blockIdx.x >> 6;
  int chunk = blockIdx.x & 63;
  if (threadIdx.x < B_) c[threadIdx.x] = comp[r * B_ + threadIdx.x];
  __syncthreads();
  int ij = chunk * 256 + threadIdx.x;
  float acc = 0.f;
#pragma unroll 10
  for (int b = 0; b < B_; b++) acc += c[b] * basis[b * (D_ * D_) + ij];
  W[r * (D_ * D_) + ij] = acc;
}

// pack: Wpack[r][ks][cg][lane][j] = bf16(W[r][ks*32+(lane>>4)*8+j][cg*16+(lane&15)])
__global__ __launch_bounds__(256) void k_packW(const float* __restrict__ W, ushort* __restrict__ Wpack) {
  int r = blockIdx.x;
  const float* Wr = W + (size_t)r * (D_ * D_);
  ushort* out = Wpack + (size_t)r * (D_ * D_);
  for (int i = threadIdx.x; i < D_ * D_; i += 256) {
    int j = i & 7, l = (i >> 3) & 63, cg = (i >> 9) & 7, ks = i >> 12;
    int k = ks * 32 + (l >> 4) * 8 + j;
    int n = cg * 16 + (l & 15);
    out[i] = f2bf(Wr[k * D_ + n]);
  }
}

__global__ __launch_bounds__(256) void k_cast(const float* __restrict__ x, ushort* __restrict__ xb, int n8) {
  int i = blockIdx.x * 256 + threadIdx.x;
  if (i >= n8) return;
  const float4* xp = (const float4*)(x + (size_t)i * 8);
  float4 a = xp[0], b = xp[1];
  uint4 pk;
  pk.x = (uint)f2bf(a.x) | ((uint)f2bf(a.y) << 16);
  pk.y = (uint)f2bf(a.z) | ((uint)f2bf(a.w) << 16);
  pk.z = (uint)f2bf(b.x) | ((uint)f2bf(b.y) << 16);
  pk.w = (uint)f2bf(b.z) | ((uint)f2bf(b.w) << 16);
  *(uint4*)(xb + (size_t)i * 8) = pk;
}

// ---------------- y = x @ root + bias (MFMA, LDS-resident W) ----------------

__global__ __launch_bounds__(256, 4) void k_root_mfma(
    const ushort* __restrict__ xb, const ushort* __restrict__ rootPack,
    const float* __restrict__ bias, float* __restrict__ y, int nt) {
  __shared__ ushort Wl[D_ * D_];   // 32 KB
  int tstart = blockIdx.x * RG_;
  if (tstart >= nt) return;
  int tend = tstart + RG_; if (tend > nt) tend = nt;
  int w = threadIdx.x >> 6, l = threadIdx.x & 63;
  int q = l >> 4, tx = l & 15;
  {
    const uint4* wp = (const uint4*)rootPack;
    uint4* wl = (uint4*)Wl;
#pragma unroll
    for (int i = 0; i < 8; ++i) wl[i * 256 + threadIdx.x] = wp[i * 256 + threadIdx.x];
  }
  float bv[8];
#pragma unroll
  for (int cg = 0; cg < 8; ++cg) bv[cg] = bias[cg * 16 + tx];
  s8b a0, a1, a2, a3;
  {
    int gr = tstart * TE + 16 * w + tx; if (gr >= N_) gr = N_ - 1;
    const s8b* xr = (const s8b*)(xb + (size_t)gr * D_);
    a0 = xr[q]; a1 = xr[4 + q]; a2 = xr[8 + q]; a3 = xr[12 + q];
  }
  __syncthreads();
  for (int tile = tstart; tile < tend; ++tile) {
    int base = tile * TE;
    s8b n0, n1, n2, n3;
    bool pre = (tile + 1 < tend);
    if (pre) {
      int gr = base + TE + 16 * w + tx; if (gr >= N_) gr = N_ - 1;
      const s8b* xn = (const s8b*)(xb + (size_t)gr * D_);
      n0 = xn[q]; n1 = xn[4 + q]; n2 = xn[8 + q]; n3 = xn[12 + q];
    }
    f32x4 acc[8];
#pragma unroll
    for (int cg = 0; cg < 8; ++cg) acc[cg] = (f32x4){0.f, 0.f, 0.f, 0.f};
#pragma unroll
    for (int cg = 0; cg < 8; ++cg) {
      s8b b0 = *(const s8b*)&Wl[((0 * 8 + cg) * 64 + l) * 8];
      s8b b1 = *(const s8b*)&Wl[((1 * 8 + cg) * 64 + l) * 8];
      s8b b2 = *(const s8b*)&Wl[((2 * 8 + cg) * 64 + l) * 8];
      s8b b3 = *(const s8b*)&Wl[((3 * 8 + cg) * 64 + l) * 8];
      acc[cg] = __builtin_amdgcn_mfma_f32_16x16x32_bf16(a0, b0, acc[cg], 0, 0, 0);
      acc[cg] = __builtin_amdgcn_mfma_f32_16x16x32_bf16(a1, b1, acc[cg], 0, 0, 0);
      acc[cg] = __builtin_amdgcn_mfma_f32_16x16x32_bf16(a2, b2, acc[cg], 0, 0, 0);
      acc[cg] = __builtin_amdgcn_mfma_f32_16x16x32_bf16(a3, b3, acc[cg], 0, 0, 0);
    }
#pragma unroll
    for (int cg = 0; cg < 8; ++cg)
#pragma unroll
      for (int r = 0; r < 4; ++r) {
        int gr = base + 16 * w + 4 * q + r;
        if (gr < N_) y[(size_t)gr * D_ + cg * 16 + tx] = acc[cg][r] + bv[cg];
      }
    if (pre) { a0 = n0; a1 = n1; a2 = n2; a3 = n3; }
  }
}

// ---------------- phase A: MFMA edge messages (LDS-resident W, persistent grid) ----------------

__global__ __launch_bounds__(256, 4) void k_edges_mfma(
    const ushort* __restrict__ xb, const ushort* __restrict__ Wpack,
    const int* __restrict__ srcS, const float* __restrict__ normS,
    const int* __restrict__ tileRel, const int* __restrict__ padOff,
    ushort* __restrict__ msg, int tile0, int tile1) {
  __shared__ ushort Wl[D_ * D_];   // 32 KB, one relation
  int padTot = padOff[R_];
  int w = threadIdx.x >> 6, l = threadIdx.x & 63;
  int q = l >> 4, tx = l & 15;
  int curRel = -1;
  for (int tb = tile0 + blockIdx.x * G_; tb < tile1; tb += gridDim.x * G_) {
    if (tb * TE >= padTot) break;
    int tend = tb + G_; if (tend > tile1) tend = tile1;
    s8b a0, a1, a2, a3;
    {
      int sr = srcS[tb * TE + 16 * w + tx];
      const s8b* xr = (const s8b*)(xb + (size_t)sr * D_);
      a0 = xr[q]; a1 = xr[4 + q]; a2 = xr[8 + q]; a3 = xr[12 + q];
    }
    for (int tile = tb; tile < tend; ++tile) {
      int base = tile * TE;
      if (base >= padTot) break;
      int rel = tileRel[tile];
      if (rel != curRel) {                    // block-uniform branch
        curRel = rel;
        __syncthreads();
        const uint4* wp = (const uint4*)(Wpack + (size_t)rel * (D_ * D_));
        uint4* wl = (uint4*)Wl;
#pragma unroll
        for (int i = 0; i < 8; ++i) wl[i * 256 + threadIdx.x] = wp[i * 256 + threadIdx.x];
        __syncthreads();
      }
      float nv[4];
#pragma unroll
      for (int r = 0; r < 4; ++r) nv[r] = normS[base + 16 * w + 4 * q + r];
      // prefetch next tile's A fragments
      s8b n0, n1, n2, n3;
      int nb = base + TE;
      bool pre = (tile + 1 < tend) && (nb < padTot);
      if (pre) {
        int sr = srcS[nb + 16 * w + tx];
        const s8b* xn = (const s8b*)(xb + (size_t)sr * D_);
        n0 = xn[q]; n1 = xn[4 + q]; n2 = xn[8 + q]; n3 = xn[12 + q];
      }
      f32x4 acc[8];
#pragma unroll
      for (int cg = 0; cg < 8; ++cg) acc[cg] = (f32x4){0.f, 0.f, 0.f, 0.f};
#pragma unroll
      for (int cg = 0; cg < 8; ++cg) {
        s8b b0 = *(const s8b*)&Wl[((0 * 8 + cg) * 64 + l) * 8];
        s8b b1 = *(const s8b*)&Wl[((1 * 8 + cg) * 64 + l) * 8];
        s8b b2 = *(const s8b*)&Wl[((2 * 8 + cg) * 64 + l) * 8];
        s8b b3 = *(const s8b*)&Wl[((3 * 8 + cg) * 64 + l) * 8];
        acc[cg] = __builtin_amdgcn_mfma_f32_16x16x32_bf16(a0, b0, acc[cg], 0, 0, 0);
        acc[cg] = __builtin_amdgcn_mfma_f32_16x16x32_bf16(a1, b1, acc[cg], 0, 0, 0);
        acc[cg] = __builtin_amdgcn_mfma_f32_16x16x32_bf16(a2, b2, acc[cg], 0, 0, 0);
        acc[cg] = __builtin_amdgcn_mfma_f32_16x16x32_bf16(a3, b3, acc[cg], 0, 0, 0);
      }
      ushort* mrow = msg + (size_t)(base - tile0 * TE + 16 * w + 4 * q) * D_;
#pragma unroll
      for (int cg = 0; cg < 8; ++cg) {
        int col = cg * 16 + tx;
#pragma unroll
        for (int r = 0; r < 4; ++r)
          __builtin_nontemporal_store(f2bf(acc[cg][r] * nv[r]), mrow + (size_t)r * D_ + col);
      }
      if (pre) { a0 = n0; a1 = n1; a2 = n2; a3 = n3; }
    }
  }
}

// ---------------- phase B: wave-per-dst aggregation ----------------

__global__ __launch_bounds__(256) void k_agg2(const ushort* __restrict__ msg, const int* __restrict__ posbuf,
                                              const int* __restrict__ jlo, const int* __restrict__ jhi,
                                              float* __restrict__ y, int plo, int final_) {
  int d = blockIdx.x * 4 + (threadIdx.x >> 6);
  if (d >= N_) return;
  int l = threadIdx.x & 63, sub = l >> 4, tx = l & 15;
  int s0 = jlo[d], s1 = jhi[d];
  float acc[8];
#pragma unroll
  for (int i = 0; i < 8; ++i) acc[i] = 0.f;
  for (int j = s0 + sub; j < s1; j += 4) {
    int p = posbuf[j];
    u32x4 mv = __builtin_nontemporal_load((const u32x4*)(msg + (((size_t)(p - plo)) << 7) + (tx << 3)));
    acc[0] += bf2f((ushort)mv[0]); acc[1] += bf2f((ushort)(mv[0] >> 16));
    acc[2] += bf2f((ushort)mv[1]); acc[3] += bf2f((ushort)(mv[1] >> 16));
    acc[4] += bf2f((ushort)mv[2]); acc[5] += bf2f((ushort)(mv[2] >> 16));
    acc[6] += bf2f((ushort)mv[3]); acc[7] += bf2f((ushort)(mv[3] >> 16));
  }
#pragma unroll
  for (int i = 0; i < 8; ++i) {
    acc[i] += __shfl_xor(acc[i], 16);
    acc[i] += __shfl_xor(acc[i], 32);
  }
  if (sub == 0) {
    float* yp = y + (((size_t)d) << 7) + (tx << 3);
    float4 y0 = *(float4*)yp, y1 = *(float4*)(yp + 4);
    y0.x += acc[0]; y0.y += acc[1]; y0.z += acc[2]; y0.w += acc[3];
    y1.x += acc[4]; y1.y += acc[5]; y1.z += acc[6]; y1.w += acc[7];
    if (final_) {
      y0.x = fmaxf(y0.x, 0.f); y0.y = fmaxf(y0.y, 0.f); y0.z = fmaxf(y0.z, 0.f); y0.w = fmaxf(y0.w, 0.f);
      y1.x = fmaxf(y1.x, 0.f); y1.y = fmaxf(y1.y, 0.f); y1.z = fmaxf(y1.z, 0.f); y1.w = fmaxf(y1.w, 0.f);
    }
    *(float4*)yp = y0; *(float4*)(yp + 4) = y1;
  }
}

// ---------------- launch ----------------

extern "C" void kernel_launch(void* const* d_in, const int* in_sizes, int n_in,
                              void* d_out, int out_size, void* d_ws, size_t ws_size,
                              hipStream_t stream) {
  const float* entity = (const float*)d_in[0];
  const float* comp   = (const float*)d_in[1];
  const float* basis  = (const float*)d_in[2];
  const float* root   = (const float*)d_in[3];
  const float* bias   = (const float*)d_in[4];
  const int*   eidx   = (const int*)d_in[5];
  const int*   etype  = (const int*)d_in[6];
  const int E = in_sizes[6];
  const int* src = eidx;
  const int* dst = eidx + E;

  char* ws = (char*)d_ws;
  const size_t Epad = (size_t)E + (size_t)R_ * TE;
  const int uTiles = (E + TE - 1) / TE + R_;
  const int NBLK = (N_ + 1 + 255) / 256;
  auto al = [](size_t x) { return (x + 255) & ~(size_t)255; };

  size_t o_Wpack  = 0;
  size_t o_srcS   = al(o_Wpack + (size_t)(R_ + 1) * D_ * D_ * 2);   // +1 slot for packed root
  size_t o_normS  = al(o_srcS + Epad * 4);
  size_t o_posbuf = al(o_normS + Epad * 4);
  size_t o_degDst = al(o_posbuf + (size_t)E * 4);
  size_t o_dstOff = al(o_degDst + (size_t)N_ * 4);
  size_t o_cursD  = al(o_dstOff + (size_t)(N_ + 8) * 4);
  size_t o_bounds = al(o_cursD + (size_t)N_ * 4);
  size_t o_tileRel= al(o_bounds + (size_t)MAXC * N_ * 4);
  size_t o_small  = al(o_tileRel + (size_t)uTiles * 4);
  size_t o_x1     = al(o_small + 8192);
  size_t o_xb     = al(o_x1 + (size_t)N_ * D_ * 4);
  size_t o_msg    = al(o_xb + (size_t)N_ * D_ * 2);

  // aliases inside the msg region (all dead before first msg write):
  size_t o_dstS   = o_msg;                 // Epad*4, dead after k_scatterDst passes
  size_t o_Wf     = al(o_msg + Epad * 4);  // per-layer, dead after k_packW (before msg writes)

  ushort* Wpack  = (ushort*)(ws + o_Wpack);
  int*    srcS   = (int*)(ws + o_srcS);
  float*  normS  = (float*)(ws + o_normS);
  int*    posbuf = (int*)(ws + o_posbuf);
  int*    degDst = (int*)(ws + o_degDst);
  int*    dstOff = (int*)(ws + o_dstOff);
  int*    cursD  = (int*)(ws + o_cursD);
  int*    bounds = (int*)(ws + o_bounds);
  int*    tileRel= (int*)(ws + o_tileRel);
  int*    hist   = (int*)(ws + o_small);
  int*    padOff = hist + 256;
  int*    cursor = hist + 512;
  int*    blkSum = hist + 768;
  int*    blkOff = hist + 1280;
  float*  x1     = (float*)(ws + o_x1);
  ushort* xb     = (ushort*)(ws + o_xb);
  int*    dstS   = (int*)(ws + o_dstS);
  float*  Wf     = (float*)(ws + o_Wf);
  ushort* msg    = (ushort*)(ws + o_msg);
  ushort* rootPack = Wpack + (size_t)R_ * D_ * D_;

  (void)hipMemsetAsync(ws + o_srcS, 0, Epad * 4, stream);
  (void)hipMemsetAsync(ws + o_degDst, 0, (size_t)N_ * 4, stream);
  (void)hipMemsetAsync(ws + o_small, 0, 8192, stream);
  (void)hipMemsetAsync(ws + o_dstS, 0xFF, Epad * 4, stream);

  int gH = (E + 4095) / 4096;
  int gE = (E + 255) / 256;
  k_hist<<<gH, 256, 0, stream>>>(etype, E, hist);
  k_scanRel<<<1, 256, 0, stream>>>(hist, padOff, cursor);
  k_scatter<<<gH, 256, 0, stream>>>(src, dst, etype, E, cursor, srcS, dstS);
  k_tileRel<<<(uTiles + 255) / 256, 256, 0, stream>>>(padOff, tileRel, uTiles);
  k_countDst<<<gE, 256, 0, stream>>>(dst, E, degDst);
  k_degPart<<<NBLK, 256, 0, stream>>>(degDst, blkSum);
  k_scanBlk<<<1, 512, 0, stream>>>(blkSum, blkOff, NBLK);
  k_writeOff<<<NBLK, 256, 0, stream>>>(degDst, blkOff, dstOff, cursD);

  // chunking from ws capacity
  size_t cap = (ws_size > o_msg + 16384) ? (ws_size - o_msg) : (size_t)16384;
  size_t tileBytes = (size_t)TE * D_ * 2;
  long long maxT = (long long)(cap / tileBytes);
  if (maxT < 1) maxT = 1;
  int nch = (int)((uTiles + maxT - 1) / maxT);
  if (nch < 1) nch = 1;
  if (nch > MAXC) nch = MAXC;
  int chunkTiles = (uTiles + nch - 1) / nch;
  nch = (uTiles + chunkTiles - 1) / chunkTiles;

  // chunk-major posbuf: scatter per chunk, snapshot cursors
  for (int c = 0; c < nch; c++) {
    int plo = c * chunkTiles * TE;
    int phi = (c + 1) * chunkTiles * TE; if (phi > uTiles * TE) phi = uTiles * TE;
    int gS = (phi - plo + 255) / 256;
    if (gS > 0)
      k_scatterDst<<<gS, 256, 0, stream>>>(dstS, padOff, cursD, posbuf, plo, phi);
    k_copyBound<<<(N_ + 255) / 256, 256, 0, stream>>>(cursD, bounds + (size_t)c * N_);
  }

  k_norm<<<(N_ + 3) / 4, 256, 0, stream>>>(posbuf, dstOff, tileRel, normS);

  int ntR = (N_ + TE - 1) / TE;
  int gAgg = (N_ + 3) / 4;
  for (int l = 0; l < 2; l++) {
    const float* xin = l ? x1 : entity;
    float* yout = l ? (float*)d_out : x1;
    k_computeW<<<R_ * 64, 256, 0, stream>>>(comp + l * R_ * B_, basis + (size_t)l * B_ * D_ * D_, Wf);
    k_packW<<<R_, 256, 0, stream>>>(Wf, Wpack);
    k_packW<<<1, 256, 0, stream>>>(root + (size_t)l * D_ * D_, rootPack);
    k_cast<<<(N_ * D_ / 8 + 255) / 256, 256, 0, stream>>>(xin, xb, N_ * D_ / 8);
    k_root_mfma<<<(ntR + RG_ - 1) / RG_, 256, 0, stream>>>(xb, rootPack, bias + l * D_, yout, ntR);
    for (int c = 0; c < nch; c++) {
      int t0 = c * chunkTiles;
      int t1 = t0 + chunkTiles; if (t1 > uTiles) t1 = uTiles;
      int nGroups = (t1 - t0 + G_ - 1) / G_;
      int gB = nGroups < 1024 ? nGroups : 1024;
      k_edges_mfma<<<gB, 256, 0, stream>>>(xb, Wpack, srcS, normS, tileRel, padOff, msg, t0, t1);
      const int* jlo = (c == 0) ? dstOff : bounds + (size_t)(c - 1) * N_;
      const int* jhi = bounds + (size_t)c * N_;
      k_agg2<<<gAgg, 256, 0, stream>>>(msg, posbuf, jlo, jhi, yout, t0 * TE, c == nch - 1);
    }
  }
}

// Round 9
// 1205.161 us; speedup vs baseline: 1.5007x; 1.5007x over previous
//
#include <hip/hip_runtime.h>
#include <hip/hip_bf16.h>
#include <stdint.h>

#define D_ 128
#define R_ 200
#define B_ 50
#define N_ 100000
#define TE 64
#define G_ 8
#define RG_ 4
#define MAXC 8

typedef __attribute__((ext_vector_type(8))) short s8b;
typedef __attribute__((ext_vector_type(4))) float f32x4;
typedef __attribute__((ext_vector_type(4))) uint u32x4;

// ---------------- helpers ----------------

__device__ __forceinline__ ushort f2bf(float f) {   // RTN-even fp32 -> bf16
  uint u = __float_as_uint(f);
  return (ushort)((u + 0x7fffu + ((u >> 16) & 1u)) >> 16);
}
__device__ __forceinline__ float bf2f(ushort u) {
  return __uint_as_float(((uint)u) << 16);
}

// ---------------- counting / sorting machinery ----------------

__global__ __launch_bounds__(256) void k_hist(const int* __restrict__ et, int E, int* __restrict__ hist) {
  __shared__ int h[R_];
  for (int i = threadIdx.x; i < R_; i += 256) h[i] = 0;
  __syncthreads();
  int base = blockIdx.x * 4096;
  for (int j = 0; j < 16; j++) {
    int i = base + j * 256 + threadIdx.x;
    if (i < E) atomicAdd(&h[et[i]], 1);
  }
  __syncthreads();
  for (int i = threadIdx.x; i < R_; i += 256) { int v = h[i]; if (v) atomicAdd(&hist[i], v); }
}

// parallel relation scan with TE-padding (1 block, 256 threads)
__global__ __launch_bounds__(256) void k_scanRel(const int* __restrict__ hist,
                                                 int* __restrict__ padOff, int* __restrict__ cursor) {
  __shared__ int s[256];
  int tid = threadIdx.x;
  int v = (tid < R_) ? ((hist[tid] + TE - 1) / TE) * TE : 0;
  s[tid] = v;
  __syncthreads();
  for (int off = 1; off < 256; off <<= 1) {
    int t = (tid >= off) ? s[tid - off] : 0;
    __syncthreads();
    s[tid] += t;
    __syncthreads();
  }
  if (tid < R_) { int e = s[tid] - v; padOff[tid] = e; cursor[tid] = e; }
  if (tid == R_ - 1) padOff[R_] = s[tid];
}

__global__ __launch_bounds__(256) void k_scatter(const int* __restrict__ src, const int* __restrict__ dst,
                                                 const int* __restrict__ et, int E,
                                                 int* __restrict__ cursor,
                                                 int* __restrict__ srcS, int* __restrict__ dstS) {
  __shared__ int h[R_];
  __shared__ int gb[R_];
  for (int i = threadIdx.x; i < R_; i += 256) h[i] = 0;
  __syncthreads();
  int base = blockIdx.x * 4096;
  int lrank[16];
#pragma unroll
  for (int j = 0; j < 16; j++) {
    int i = base + j * 256 + threadIdx.x;
    lrank[j] = (i < E) ? atomicAdd(&h[et[i]], 1) : 0;
  }
  __syncthreads();
  for (int i = threadIdx.x; i < R_; i += 256) { int v = h[i]; gb[i] = v ? atomicAdd(&cursor[i], v) : 0; }
  __syncthreads();
#pragma unroll
  for (int j = 0; j < 16; j++) {
    int i = base + j * 256 + threadIdx.x;
    if (i < E) {
      int r = et[i];
      int pos = gb[r] + lrank[j];
      srcS[pos] = src[i];
      dstS[pos] = dst[i];
    }
  }
}

__global__ __launch_bounds__(256) void k_tileRel(const int* __restrict__ padOff, int* __restrict__ tileRel, int uT) {
  int t = blockIdx.x * 256 + threadIdx.x;
  if (t >= uT) return;
  int base = t * TE;
  if (base >= padOff[R_]) { tileRel[t] = 0; return; }
  int lo = 0, hi = R_ - 1;
  while (lo < hi) { int mid = (lo + hi + 1) >> 1; if (padOff[mid] <= base) lo = mid; else hi = mid - 1; }
  tileRel[t] = lo;
}

// ---------------- dst-sort: parallel 3-kernel scan ----------------

__global__ __launch_bounds__(256) void k_countDst(const int* __restrict__ dst, int E, int* __restrict__ deg) {
  int i = blockIdx.x * 256 + threadIdx.x;
  if (i < E) atomicAdd(&deg[dst[i]], 1);
}

__global__ __launch_bounds__(256) void k_degPart(const int* __restrict__ deg, int* __restrict__ blkSum) {
  __shared__ int ws_[4];
  int i = blockIdx.x * 256 + threadIdx.x;
  int v = (i < N_) ? deg[i] : 0;
#pragma unroll
  for (int off = 32; off >= 1; off >>= 1) v += __shfl_down(v, off);
  if ((threadIdx.x & 63) == 0) ws_[threadIdx.x >> 6] = v;
  __syncthreads();
  if (threadIdx.x == 0) blkSum[blockIdx.x] = ws_[0] + ws_[1] + ws_[2] + ws_[3];
}

__global__ __launch_bounds__(512) void k_scanBlk(const int* __restrict__ blkSum, int* __restrict__ blkOff, int nblk) {
  __shared__ int s[512];
  int tid = threadIdx.x;
  int v = (tid < nblk) ? blkSum[tid] : 0;
  s[tid] = v;
  __syncthreads();
  for (int off = 1; off < 512; off <<= 1) {
    int t = (tid >= off) ? s[tid - off] : 0;
    __syncthreads();
    s[tid] += t;
    __syncthreads();
  }
  if (tid < nblk) blkOff[tid] = s[tid] - v;   // exclusive
}

__global__ __launch_bounds__(256) void k_writeOff(const int* __restrict__ deg, const int* __restrict__ blkOff,
                                                  int* __restrict__ dstOff, int* __restrict__ cur) {
  __shared__ int s[256];
  int i = blockIdx.x * 256 + threadIdx.x;
  int tid = threadIdx.x;
  int v = (i < N_) ? deg[i] : 0;
  s[tid] = v;
  __syncthreads();
  for (int off = 1; off < 256; off <<= 1) {
    int t = (tid >= off) ? s[tid - off] : 0;
    __syncthreads();
    s[tid] += t;
    __syncthreads();
  }
  int e = blkOff[blockIdx.x] + s[tid] - v;    // global exclusive prefix
  if (i < N_) { dstOff[i] = e; cur[i] = e; }
  else if (i == N_) dstOff[N_] = e;
}

__global__ __launch_bounds__(256) void k_scatterDst(const int* __restrict__ dstS,
                                                    const int* __restrict__ padOff, int* __restrict__ cur,
                                                    int* __restrict__ posbuf, int plo, int phi) {
  int p = plo + blockIdx.x * 256 + threadIdx.x;
  if (p >= phi || p >= padOff[R_]) return;
  int d = dstS[p];
  if (d < 0) return;                 // padding slot
  int j = atomicAdd(&cur[d], 1);
  posbuf[j] = p;
}

__global__ __launch_bounds__(256) void k_copyBound(const int* __restrict__ cur, int* __restrict__ bnd) {
  int d = blockIdx.x * 256 + threadIdx.x;
  if (d < N_) bnd[d] = cur[d];
}

// ---------------- per-edge mean-norm from dst-sorted segments ----------------

__global__ __launch_bounds__(256) void k_norm(const int* __restrict__ posbuf, const int* __restrict__ dstOff,
                                              const int* __restrict__ tileRel, float* __restrict__ normS) {
  __shared__ int rels[4][128];
  int d = blockIdx.x * 4 + (threadIdx.x >> 6);
  int sub = threadIdx.x >> 6;
  int l = threadIdx.x & 63;
  int s0 = 0, deg = 0;
  if (d < N_) { s0 = dstOff[d]; deg = dstOff[d + 1] - s0; }
  int cap = deg < 128 ? deg : 128;
  int myp[4]; int myr[4];
  for (int j = l, t = 0; j < cap; j += 64, ++t) {
    int p = posbuf[s0 + j];
    int r = tileRel[p >> 6];
    rels[sub][j] = r;
    if (t < 4) { myp[t] = p; myr[t] = r; }
  }
  __syncthreads();
  if (d >= N_) return;
  for (int j = l, t = 0; j < deg; j += 64, ++t) {
    int p, r;
    if (j < 128 && t < 4) { p = myp[t]; r = myr[t]; }
    else { p = posbuf[s0 + j]; r = tileRel[p >> 6]; }
    int cnt = 0;
    for (int k = 0; k < deg; k++) {
      int rk = (k < 128) ? rels[sub][k] : tileRel[posbuf[s0 + k] >> 6];
      cnt += (rk == r) ? 1 : 0;
    }
    normS[p] = 1.0f / (float)(cnt > 0 ? cnt : 1);
  }
}

// ---------------- W_r = sum_b comp[r,b]*basis[b]; pack to B-fragment order ----------------

__global__ __launch_bounds__(256) void k_computeW(const float* __restrict__ comp, const float* __restrict__ basis,
                                                  float* __restrict__ W) {
  __shared__ float c[B_];
  int r = blockIdx.x >> 6;
  int chunk = blockIdx.x & 63;
  if (threadIdx.x < B_) c[threadIdx.x] = comp[r * B_ + threadIdx.x];
  __syncthreads();
  int ij = chunk * 256 + threadIdx.x;
  float acc = 0.f;
#pragma unroll 10
  for (int b = 0; b < B_; b++) acc += c[b] * basis[b * (D_ * D_) + ij];
  W[r * (D_ * D_) + ij] = acc;
}

// pack: Wpack[r][ks][cg][lane][j] = bf16(W[r][ks*32+(lane>>4)*8+j][cg*16+(lane&15)])
__global__ __launch_bounds__(256) void k_packW(const float* __restrict__ W, ushort* __restrict__ Wpack) {
  int r = blockIdx.x;
  const float* Wr = W + (size_t)r * (D_ * D_);
  ushort* out = Wpack + (size_t)r * (D_ * D_);
  for (int i = threadIdx.x; i < D_ * D_; i += 256) {
    int j = i & 7, l = (i >> 3) & 63, cg = (i >> 9) & 7, ks = i >> 12;
    int k = ks * 32 + (l >> 4) * 8 + j;
    int n = cg * 16 + (l & 15);
    out[i] = f2bf(Wr[k * D_ + n]);
  }
}

__global__ __launch_bounds__(256) void k_cast(const float* __restrict__ x, ushort* __restrict__ xb, int n8) {
  int i = blockIdx.x * 256 + threadIdx.x;
  if (i >= n8) return;
  const float4* xp = (const float4*)(x + (size_t)i * 8);
  float4 a = xp[0], b = xp[1];
  uint4 pk;
  pk.x = (uint)f2bf(a.x) | ((uint)f2bf(a.y) << 16);
  pk.y = (uint)f2bf(a.z) | ((uint)f2bf(a.w) << 16);
  pk.z = (uint)f2bf(b.x) | ((uint)f2bf(b.y) << 16);
  pk.w = (uint)f2bf(b.z) | ((uint)f2bf(b.w) << 16);
  *(uint4*)(xb + (size_t)i * 8) = pk;
}

// ---------------- y = x @ root + bias (MFMA, LDS-resident W) ----------------

__global__ __launch_bounds__(256, 4) void k_root_mfma(
    const ushort* __restrict__ xb, const ushort* __restrict__ rootPack,
    const float* __restrict__ bias, float* __restrict__ y, int nt) {
  __shared__ ushort Wl[D_ * D_];   // 32 KB
  int tstart = blockIdx.x * RG_;
  if (tstart >= nt) return;
  int tend = tstart + RG_; if (tend > nt) tend = nt;
  int w = threadIdx.x >> 6, l = threadIdx.x & 63;
  int q = l >> 4, tx = l & 15;
  {
    const uint4* wp = (const uint4*)rootPack;
    uint4* wl = (uint4*)Wl;
#pragma unroll
    for (int i = 0; i < 8; ++i) wl[i * 256 + threadIdx.x] = wp[i * 256 + threadIdx.x];
  }
  float bv[8];
#pragma unroll
  for (int cg = 0; cg < 8; ++cg) bv[cg] = bias[cg * 16 + tx];
  s8b a0, a1, a2, a3;
  {
    int gr = tstart * TE + 16 * w + tx; if (gr >= N_) gr = N_ - 1;
    const s8b* xr = (const s8b*)(xb + (size_t)gr * D_);
    a0 = xr[q]; a1 = xr[4 + q]; a2 = xr[8 + q]; a3 = xr[12 + q];
  }
  __syncthreads();
  for (int tile = tstart; tile < tend; ++tile) {
    int base = tile * TE;
    s8b n0, n1, n2, n3;
    bool pre = (tile + 1 < tend);
    if (pre) {
      int gr = base + TE + 16 * w + tx; if (gr >= N_) gr = N_ - 1;
      const s8b* xn = (const s8b*)(xb + (size_t)gr * D_);
      n0 = xn[q]; n1 = xn[4 + q]; n2 = xn[8 + q]; n3 = xn[12 + q];
    }
    f32x4 acc[8];
#pragma unroll
    for (int cg = 0; cg < 8; ++cg) acc[cg] = (f32x4){0.f, 0.f, 0.f, 0.f};
#pragma unroll
    for (int cg = 0; cg < 8; ++cg) {
      s8b b0 = *(const s8b*)&Wl[((0 * 8 + cg) * 64 + l) * 8];
      s8b b1 = *(const s8b*)&Wl[((1 * 8 + cg) * 64 + l) * 8];
      s8b b2 = *(const s8b*)&Wl[((2 * 8 + cg) * 64 + l) * 8];
      s8b b3 = *(const s8b*)&Wl[((3 * 8 + cg) * 64 + l) * 8];
      acc[cg] = __builtin_amdgcn_mfma_f32_16x16x32_bf16(a0, b0, acc[cg], 0, 0, 0);
      acc[cg] = __builtin_amdgcn_mfma_f32_16x16x32_bf16(a1, b1, acc[cg], 0, 0, 0);
      acc[cg] = __builtin_amdgcn_mfma_f32_16x16x32_bf16(a2, b2, acc[cg], 0, 0, 0);
      acc[cg] = __builtin_amdgcn_mfma_f32_16x16x32_bf16(a3, b3, acc[cg], 0, 0, 0);
    }
#pragma unroll
    for (int cg = 0; cg < 8; ++cg)
#pragma unroll
      for (int r = 0; r < 4; ++r) {
        int gr = base + 16 * w + 4 * q + r;
        if (gr < N_) y[(size_t)gr * D_ + cg * 16 + tx] = acc[cg][r] + bv[cg];
      }
    if (pre) { a0 = n0; a1 = n1; a2 = n2; a3 = n3; }
  }
}

// ---------------- phase A: MFMA edge messages ----------------
// LDS-resident W + wave-private staging tile for full-128B-line msg stores.

__global__ __launch_bounds__(256, 4) void k_edges_mfma(
    const ushort* __restrict__ xb, const ushort* __restrict__ Wpack,
    const int* __restrict__ srcS, const float* __restrict__ normS,
    const int* __restrict__ tileRel, const int* __restrict__ padOff,
    ushort* __restrict__ msg, int tile0, int tile1) {
  __shared__ ushort Wl[D_ * D_];        // 32 KB, one relation
  __shared__ ushort stg[4][16 * 136];   // 17 KB, wave-private staging (pad 136)
  int padTot = padOff[R_];
  int w = threadIdx.x >> 6, l = threadIdx.x & 63;
  int q = l >> 4, tx = l & 15;
  int g = l >> 3, m = l & 7;
  ushort* st = stg[w];
  int curRel = -1;
  for (int tb = tile0 + blockIdx.x * G_; tb < tile1; tb += gridDim.x * G_) {
    if (tb * TE >= padTot) break;
    int tend = tb + G_; if (tend > tile1) tend = tile1;
    s8b a0, a1, a2, a3;
    {
      int sr = srcS[tb * TE + 16 * w + tx];
      const s8b* xr = (const s8b*)(xb + (size_t)sr * D_);
      a0 = xr[q]; a1 = xr[4 + q]; a2 = xr[8 + q]; a3 = xr[12 + q];
    }
    for (int tile = tb; tile < tend; ++tile) {
      int base = tile * TE;
      if (base >= padTot) break;
      int rel = tileRel[tile];
      if (rel != curRel) {                    // block-uniform branch
        curRel = rel;
        __syncthreads();
        const uint4* wp = (const uint4*)(Wpack + (size_t)rel * (D_ * D_));
        uint4* wl = (uint4*)Wl;
#pragma unroll
        for (int i = 0; i < 8; ++i) wl[i * 256 + threadIdx.x] = wp[i * 256 + threadIdx.x];
        __syncthreads();
      }
      float nv[4];
#pragma unroll
      for (int r = 0; r < 4; ++r) nv[r] = normS[base + 16 * w + 4 * q + r];
      // prefetch next tile's A fragments
      s8b n0, n1, n2, n3;
      int nb = base + TE;
      bool pre = (tile + 1 < tend) && (nb < padTot);
      if (pre) {
        int sr = srcS[nb + 16 * w + tx];
        const s8b* xn = (const s8b*)(xb + (size_t)sr * D_);
        n0 = xn[q]; n1 = xn[4 + q]; n2 = xn[8 + q]; n3 = xn[12 + q];
      }
      f32x4 acc[8];
#pragma unroll
      for (int cg = 0; cg < 8; ++cg) acc[cg] = (f32x4){0.f, 0.f, 0.f, 0.f};
#pragma unroll
      for (int cg = 0; cg < 8; ++cg) {
        s8b b0 = *(const s8b*)&Wl[((0 * 8 + cg) * 64 + l) * 8];
        s8b b1 = *(const s8b*)&Wl[((1 * 8 + cg) * 64 + l) * 8];
        s8b b2 = *(const s8b*)&Wl[((2 * 8 + cg) * 64 + l) * 8];
        s8b b3 = *(const s8b*)&Wl[((3 * 8 + cg) * 64 + l) * 8];
        acc[cg] = __builtin_amdgcn_mfma_f32_16x16x32_bf16(a0, b0, acc[cg], 0, 0, 0);
        acc[cg] = __builtin_amdgcn_mfma_f32_16x16x32_bf16(a1, b1, acc[cg], 0, 0, 0);
        acc[cg] = __builtin_amdgcn_mfma_f32_16x16x32_bf16(a2, b2, acc[cg], 0, 0, 0);
        acc[cg] = __builtin_amdgcn_mfma_f32_16x16x32_bf16(a3, b3, acc[cg], 0, 0, 0);
      }
      // stage to wave-private LDS (no barrier; in-wave lgkmcnt ordering)
#pragma unroll
      for (int cg = 0; cg < 8; ++cg)
#pragma unroll
        for (int r = 0; r < 4; ++r)
          st[(4 * q + r) * 136 + cg * 16 + tx] = f2bf(acc[cg][r] * nv[r]);
      // write back as full 128B lines: 4 instrs, each 8 rows x 128B aligned
      ushort* mbase = msg + (size_t)(base - tile0 * TE + 16 * w) * D_;
#pragma unroll
      for (int jj = 0; jj < 2; ++jj)
#pragma unroll
        for (int hh = 0; hh < 2; ++hh) {
          int row = 8 * jj + g;
          u32x4 v = *(const u32x4*)&st[row * 136 + hh * 64 + m * 8];
          *(u32x4*)(mbase + (size_t)row * D_ + hh * 64 + m * 8) = v;
        }
      if (pre) { a0 = n0; a1 = n1; a2 = n2; a3 = n3; }
    }
  }
}

// ---------------- phase B: wave-per-dst aggregation ----------------

__global__ __launch_bounds__(256) void k_agg2(const ushort* __restrict__ msg, const int* __restrict__ posbuf,
                                              const int* __restrict__ jlo, const int* __restrict__ jhi,
                                              float* __restrict__ y, int plo, int final_) {
  int d = blockIdx.x * 4 + (threadIdx.x >> 6);
  if (d >= N_) return;
  int l = threadIdx.x & 63, sub = l >> 4, tx = l & 15;
  int s0 = jlo[d], s1 = jhi[d];
  float acc[8];
#pragma unroll
  for (int i = 0; i < 8; ++i) acc[i] = 0.f;
  for (int j = s0 + sub; j < s1; j += 4) {
    int p = posbuf[j];
    u32x4 mv = *(const u32x4*)(msg + (((size_t)(p - plo)) << 7) + (tx << 3));
    acc[0] += bf2f((ushort)mv[0]); acc[1] += bf2f((ushort)(mv[0] >> 16));
    acc[2] += bf2f((ushort)mv[1]); acc[3] += bf2f((ushort)(mv[1] >> 16));
    acc[4] += bf2f((ushort)mv[2]); acc[5] += bf2f((ushort)(mv[2] >> 16));
    acc[6] += bf2f((ushort)mv[3]); acc[7] += bf2f((ushort)(mv[3] >> 16));
  }
#pragma unroll
  for (int i = 0; i < 8; ++i) {
    acc[i] += __shfl_xor(acc[i], 16);
    acc[i] += __shfl_xor(acc[i], 32);
  }
  if (sub == 0) {
    float* yp = y + (((size_t)d) << 7) + (tx << 3);
    float4 y0 = *(float4*)yp, y1 = *(float4*)(yp + 4);
    y0.x += acc[0]; y0.y += acc[1]; y0.z += acc[2]; y0.w += acc[3];
    y1.x += acc[4]; y1.y += acc[5]; y1.z += acc[6]; y1.w += acc[7];
    if (final_) {
      y0.x = fmaxf(y0.x, 0.f); y0.y = fmaxf(y0.y, 0.f); y0.z = fmaxf(y0.z, 0.f); y0.w = fmaxf(y0.w, 0.f);
      y1.x = fmaxf(y1.x, 0.f); y1.y = fmaxf(y1.y, 0.f); y1.z = fmaxf(y1.z, 0.f); y1.w = fmaxf(y1.w, 0.f);
    }
    *(float4*)yp = y0; *(float4*)(yp + 4) = y1;
  }
}

// ---------------- launch ----------------

extern "C" void kernel_launch(void* const* d_in, const int* in_sizes, int n_in,
                              void* d_out, int out_size, void* d_ws, size_t ws_size,
                              hipStream_t stream) {
  const float* entity = (const float*)d_in[0];
  const float* comp   = (const float*)d_in[1];
  const float* basis  = (const float*)d_in[2];
  const float* root   = (const float*)d_in[3];
  const float* bias   = (const float*)d_in[4];
  const int*   eidx   = (const int*)d_in[5];
  const int*   etype  = (const int*)d_in[6];
  const int E = in_sizes[6];
  const int* src = eidx;
  const int* dst = eidx + E;

  char* ws = (char*)d_ws;
  const size_t Epad = (size_t)E + (size_t)R_ * TE;
  const int uTiles = (E + TE - 1) / TE + R_;
  const int NBLK = (N_ + 1 + 255) / 256;
  auto al = [](size_t x) { return (x + 255) & ~(size_t)255; };

  size_t o_Wpack  = 0;
  size_t o_srcS   = al(o_Wpack + (size_t)(R_ + 1) * D_ * D_ * 2);   // +1 slot for packed root
  size_t o_normS  = al(o_srcS + Epad * 4);
  size_t o_posbuf = al(o_normS + Epad * 4);
  size_t o_degDst = al(o_posbuf + (size_t)E * 4);
  size_t o_dstOff = al(o_degDst + (size_t)N_ * 4);
  size_t o_cursD  = al(o_dstOff + (size_t)(N_ + 8) * 4);
  size_t o_bounds = al(o_cursD + (size_t)N_ * 4);
  size_t o_tileRel= al(o_bounds + (size_t)MAXC * N_ * 4);
  size_t o_small  = al(o_tileRel + (size_t)uTiles * 4);
  size_t o_x1     = al(o_small + 8192);
  size_t o_xb     = al(o_x1 + (size_t)N_ * D_ * 4);
  size_t o_msg    = al(o_xb + (size_t)N_ * D_ * 2);

  // aliases inside the msg region (all dead before first msg write):
  size_t o_dstS   = o_msg;                 // Epad*4, dead after k_scatterDst passes
  size_t o_Wf     = al(o_msg + Epad * 4);  // per-layer, dead after k_packW (before msg writes)

  ushort* Wpack  = (ushort*)(ws + o_Wpack);
  int*    srcS   = (int*)(ws + o_srcS);
  float*  normS  = (float*)(ws + o_normS);
  int*    posbuf = (int*)(ws + o_posbuf);
  int*    degDst = (int*)(ws + o_degDst);
  int*    dstOff = (int*)(ws + o_dstOff);
  int*    cursD  = (int*)(ws + o_cursD);
  int*    bounds = (int*)(ws + o_bounds);
  int*    tileRel= (int*)(ws + o_tileRel);
  int*    hist   = (int*)(ws + o_small);
  int*    padOff = hist + 256;
  int*    cursor = hist + 512;
  int*    blkSum = hist + 768;
  int*    blkOff = hist + 1280;
  float*  x1     = (float*)(ws + o_x1);
  ushort* xb     = (ushort*)(ws + o_xb);
  int*    dstS   = (int*)(ws + o_dstS);
  float*  Wf     = (float*)(ws + o_Wf);
  ushort* msg    = (ushort*)(ws + o_msg);
  ushort* rootPack = Wpack + (size_t)R_ * D_ * D_;

  (void)hipMemsetAsync(ws + o_srcS, 0, Epad * 4, stream);
  (void)hipMemsetAsync(ws + o_degDst, 0, (size_t)N_ * 4, stream);
  (void)hipMemsetAsync(ws + o_small, 0, 8192, stream);
  (void)hipMemsetAsync(ws + o_dstS, 0xFF, Epad * 4, stream);

  int gH = (E + 4095) / 4096;
  int gE = (E + 255) / 256;
  k_hist<<<gH, 256, 0, stream>>>(etype, E, hist);
  k_scanRel<<<1, 256, 0, stream>>>(hist, padOff, cursor);
  k_scatter<<<gH, 256, 0, stream>>>(src, dst, etype, E, cursor, srcS, dstS);
  k_tileRel<<<(uTiles + 255) / 256, 256, 0, stream>>>(padOff, tileRel, uTiles);
  k_countDst<<<gE, 256, 0, stream>>>(dst, E, degDst);
  k_degPart<<<NBLK, 256, 0, stream>>>(degDst, blkSum);
  k_scanBlk<<<1, 512, 0, stream>>>(blkSum, blkOff, NBLK);
  k_writeOff<<<NBLK, 256, 0, stream>>>(degDst, blkOff, dstOff, cursD);

  // chunking: ws capacity AND L3-residency target (~96MB per chunk)
  size_t cap = (ws_size > o_msg + 16384) ? (ws_size - o_msg) : (size_t)16384;
  size_t tileBytes = (size_t)TE * D_ * 2;
  long long maxT = (long long)(cap / tileBytes);
  if (maxT < 1) maxT = 1;
  int nch = (int)((uTiles + maxT - 1) / maxT);
  if (nch < 1) nch = 1;
  size_t totalMsg = (size_t)uTiles * tileBytes;
  int nchT = (int)((totalMsg + ((size_t)96 << 20) - 1) / ((size_t)96 << 20));
  if (nch < nchT) nch = nchT;
  if (nch > MAXC) nch = MAXC;
  int chunkTiles = (uTiles + nch - 1) / nch;
  nch = (uTiles + chunkTiles - 1) / chunkTiles;

  // chunk-major posbuf: scatter per chunk, snapshot cursors
  for (int c = 0; c < nch; c++) {
    int plo = c * chunkTiles * TE;
    int phi = (c + 1) * chunkTiles * TE; if (phi > uTiles * TE) phi = uTiles * TE;
    int gS = (phi - plo + 255) / 256;
    if (gS > 0)
      k_scatterDst<<<gS, 256, 0, stream>>>(dstS, padOff, cursD, posbuf, plo, phi);
    k_copyBound<<<(N_ + 255) / 256, 256, 0, stream>>>(cursD, bounds + (size_t)c * N_);
  }

  k_norm<<<(N_ + 3) / 4, 256, 0, stream>>>(posbuf, dstOff, tileRel, normS);

  int ntR = (N_ + TE - 1) / TE;
  int gAgg = (N_ + 3) / 4;
  for (int l = 0; l < 2; l++) {
    const float* xin = l ? x1 : entity;
    float* yout = l ? (float*)d_out : x1;
    k_computeW<<<R_ * 64, 256, 0, stream>>>(comp + l * R_ * B_, basis + (size_t)l * B_ * D_ * D_, Wf);
    k_packW<<<R_, 256, 0, stream>>>(Wf, Wpack);
    k_packW<<<1, 256, 0, stream>>>(root + (size_t)l * D_ * D_, rootPack);
    k_cast<<<(N_ * D_ / 8 + 255) / 256, 256, 0, stream>>>(xin, xb, N_ * D_ / 8);
    k_root_mfma<<<(ntR + RG_ - 1) / RG_, 256, 0, stream>>>(xb, rootPack, bias + l * D_, yout, ntR);
    for (int c = 0; c < nch; c++) {
      int t0 = c * chunkTiles;
      int t1 = t0 + chunkTiles; if (t1 > uTiles) t1 = uTiles;
      int nGroups = (t1 - t0 + G_ - 1) / G_;
      int gB = nGroups < 1024 ? nGroups : 1024;
      k_edges_mfma<<<gB, 256, 0, stream>>>(xb, Wpack, srcS, normS, tileRel, padOff, msg, t0, t1);
      const int* jlo = (c == 0) ? dstOff : bounds + (size_t)(c - 1) * N_;
      const int* jhi = bounds + (size_t)c * N_;
      k_agg2<<<gAgg, 256, 0, stream>>>(msg, posbuf, jlo, jhi, yout, t0 * TE, c == nch - 1);
    }
  }
}

// Round 10
// 1156.234 us; speedup vs baseline: 1.5642x; 1.0423x over previous
//
#include <hip/hip_runtime.h>
#include <hip/hip_bf16.h>
#include <stdint.h>

#define D_ 128
#define R_ 200
#define B_ 50
#define N_ 100000
#define TE 64
#define RG_ 2
#define MAXC 8

typedef __attribute__((ext_vector_type(8))) short s8b;
typedef __attribute__((ext_vector_type(4))) float f32x4;
typedef __attribute__((ext_vector_type(4))) uint u32x4;

// ---------------- helpers ----------------

__device__ __forceinline__ ushort f2bf(float f) {   // RTN-even fp32 -> bf16
  uint u = __float_as_uint(f);
  return (ushort)((u + 0x7fffu + ((u >> 16) & 1u)) >> 16);
}
__device__ __forceinline__ float bf2f(ushort u) {
  return __uint_as_float(((uint)u) << 16);
}

// ---------------- counting / sorting machinery ----------------

__global__ __launch_bounds__(256) void k_hist(const int* __restrict__ et, int E, int* __restrict__ hist) {
  __shared__ int h[R_];
  for (int i = threadIdx.x; i < R_; i += 256) h[i] = 0;
  __syncthreads();
  int base = blockIdx.x * 4096;
  for (int j = 0; j < 16; j++) {
    int i = base + j * 256 + threadIdx.x;
    if (i < E) atomicAdd(&h[et[i]], 1);
  }
  __syncthreads();
  for (int i = threadIdx.x; i < R_; i += 256) { int v = h[i]; if (v) atomicAdd(&hist[i], v); }
}

// parallel relation scan with TE-padding (1 block, 256 threads)
__global__ __launch_bounds__(256) void k_scanRel(const int* __restrict__ hist,
                                                 int* __restrict__ padOff, int* __restrict__ cursor) {
  __shared__ int s[256];
  int tid = threadIdx.x;
  int v = (tid < R_) ? ((hist[tid] + TE - 1) / TE) * TE : 0;
  s[tid] = v;
  __syncthreads();
  for (int off = 1; off < 256; off <<= 1) {
    int t = (tid >= off) ? s[tid - off] : 0;
    __syncthreads();
    s[tid] += t;
    __syncthreads();
  }
  if (tid < R_) { int e = s[tid] - v; padOff[tid] = e; cursor[tid] = e; }
  if (tid == R_ - 1) padOff[R_] = s[tid];
}

// relation-sort scatter + dst-degree count fused (one pass over edges)
__global__ __launch_bounds__(256) void k_scatter(const int* __restrict__ src, const int* __restrict__ dst,
                                                 const int* __restrict__ et, int E,
                                                 int* __restrict__ cursor,
                                                 int2* __restrict__ srcdst, int* __restrict__ deg) {
  __shared__ int h[R_];
  __shared__ int gb[R_];
  for (int i = threadIdx.x; i < R_; i += 256) h[i] = 0;
  __syncthreads();
  int base = blockIdx.x * 4096;
  int lrank[16];
#pragma unroll
  for (int j = 0; j < 16; j++) {
    int i = base + j * 256 + threadIdx.x;
    lrank[j] = (i < E) ? atomicAdd(&h[et[i]], 1) : 0;
  }
  __syncthreads();
  for (int i = threadIdx.x; i < R_; i += 256) { int v = h[i]; gb[i] = v ? atomicAdd(&cursor[i], v) : 0; }
  __syncthreads();
#pragma unroll
  for (int j = 0; j < 16; j++) {
    int i = base + j * 256 + threadIdx.x;
    if (i < E) {
      int r = et[i], d = dst[i];
      int pos = gb[r] + lrank[j];
      int2 sd; sd.x = src[i]; sd.y = d;
      srcdst[pos] = sd;
      atomicAdd(&deg[d], 1);
    }
  }
}

__global__ __launch_bounds__(256) void k_tileRel(const int* __restrict__ padOff, int* __restrict__ tileRel, int uT) {
  int t = blockIdx.x * 256 + threadIdx.x;
  if (t >= uT) return;
  int base = t * TE;
  if (base >= padOff[R_]) { tileRel[t] = 0; return; }
  int lo = 0, hi = R_ - 1;
  while (lo < hi) { int mid = (lo + hi + 1) >> 1; if (padOff[mid] <= base) lo = mid; else hi = mid - 1; }
  tileRel[t] = lo;
}

// ---------------- dst-sort: parallel 3-kernel scan ----------------

__global__ __launch_bounds__(256) void k_degPart(const int* __restrict__ deg, int* __restrict__ blkSum) {
  __shared__ int ws_[4];
  int i = blockIdx.x * 256 + threadIdx.x;
  int v = (i < N_) ? deg[i] : 0;
#pragma unroll
  for (int off = 32; off >= 1; off >>= 1) v += __shfl_down(v, off);
  if ((threadIdx.x & 63) == 0) ws_[threadIdx.x >> 6] = v;
  __syncthreads();
  if (threadIdx.x == 0) blkSum[blockIdx.x] = ws_[0] + ws_[1] + ws_[2] + ws_[3];
}

__global__ __launch_bounds__(512) void k_scanBlk(const int* __restrict__ blkSum, int* __restrict__ blkOff, int nblk) {
  __shared__ int s[512];
  int tid = threadIdx.x;
  int v = (tid < nblk) ? blkSum[tid] : 0;
  s[tid] = v;
  __syncthreads();
  for (int off = 1; off < 512; off <<= 1) {
    int t = (tid >= off) ? s[tid - off] : 0;
    __syncthreads();
    s[tid] += t;
    __syncthreads();
  }
  if (tid < nblk) blkOff[tid] = s[tid] - v;   // exclusive
}

__global__ __launch_bounds__(256) void k_writeOff(const int* __restrict__ deg, const int* __restrict__ blkOff,
                                                  int* __restrict__ dstOff, int* __restrict__ cur) {
  __shared__ int s[256];
  int i = blockIdx.x * 256 + threadIdx.x;
  int tid = threadIdx.x;
  int v = (i < N_) ? deg[i] : 0;
  s[tid] = v;
  __syncthreads();
  for (int off = 1; off < 256; off <<= 1) {
    int t = (tid >= off) ? s[tid - off] : 0;
    __syncthreads();
    s[tid] += t;
    __syncthreads();
  }
  int e = blkOff[blockIdx.x] + s[tid] - v;    // global exclusive prefix
  if (i < N_) { dstOff[i] = e; cur[i] = e; }
  else if (i == N_) dstOff[N_] = e;
}

__global__ __launch_bounds__(256) void k_scatterDst(const int2* __restrict__ srcdst,
                                                    const int* __restrict__ padOff, int* __restrict__ cur,
                                                    int* __restrict__ posbuf, int plo, int phi) {
  int p = plo + blockIdx.x * 256 + threadIdx.x;
  if (p >= phi || p >= padOff[R_]) return;
  int d = srcdst[p].y;
  if (d < 0) return;                 // padding slot
  int j = atomicAdd(&cur[d], 1);
  posbuf[j] = p;
}

__global__ __launch_bounds__(256) void k_copyBound(const int* __restrict__ cur, int* __restrict__ bnd) {
  int d = blockIdx.x * 256 + threadIdx.x;
  if (d < N_) bnd[d] = cur[d];
}

// ---------------- per-edge mean-norm from dst-sorted segments ----------------

__global__ __launch_bounds__(256) void k_norm(const int* __restrict__ posbuf, const int* __restrict__ dstOff,
                                              const int* __restrict__ tileRel, float* __restrict__ normS) {
  __shared__ int rels[4][128];
  int d = blockIdx.x * 4 + (threadIdx.x >> 6);
  int sub = threadIdx.x >> 6;
  int l = threadIdx.x & 63;
  int s0 = 0, deg = 0;
  if (d < N_) { s0 = dstOff[d]; deg = dstOff[d + 1] - s0; }
  int cap = deg < 128 ? deg : 128;
  int myp[4]; int myr[4];
  for (int j = l, t = 0; j < cap; j += 64, ++t) {
    int p = posbuf[s0 + j];
    int r = tileRel[p >> 6];
    rels[sub][j] = r;
    if (t < 4) { myp[t] = p; myr[t] = r; }
  }
  __syncthreads();
  if (d >= N_) return;
  for (int j = l, t = 0; j < deg; j += 64, ++t) {
    int p, r;
    if (j < 128 && t < 4) { p = myp[t]; r = myr[t]; }
    else { p = posbuf[s0 + j]; r = tileRel[p >> 6]; }
    int cnt = 0;
    for (int k = 0; k < deg; k++) {
      int rk = (k < 128) ? rels[sub][k] : tileRel[posbuf[s0 + k] >> 6];
      cnt += (rk == r) ? 1 : 0;
    }
    normS[p] = 1.0f / (float)(cnt > 0 ? cnt : 1);
  }
}

// ---------------- W_r = sum_b comp[r,b]*basis[b]; pack to B-fragment order ----------------

__global__ __launch_bounds__(256) void k_computeW(const float* __restrict__ comp, const float* __restrict__ basis,
                                                  float* __restrict__ W) {
  __shared__ float c[B_];
  int r = blockIdx.x >> 6;
  int chunk = blockIdx.x & 63;
  if (threadIdx.x < B_) c[threadIdx.x] = comp[r * B_ + threadIdx.x];
  __syncthreads();
  int ij = chunk * 256 + threadIdx.x;
  float acc = 0.f;
#pragma unroll 10
  for (int b = 0; b < B_; b++) acc += c[b] * basis[b * (D_ * D_) + ij];
  W[r * (D_ * D_) + ij] = acc;
}

// pack: Wpack[r][ks][cg][lane][j] = bf16(W[r][ks*32+(lane>>4)*8+j][cg*16+(lane&15)])
__global__ __launch_bounds__(256) void k_packW(const float* __restrict__ W, ushort* __restrict__ Wpack) {
  int r = blockIdx.x;
  const float* Wr = W + (size_t)r * (D_ * D_);
  ushort* out = Wpack + (size_t)r * (D_ * D_);
  for (int i = threadIdx.x; i < D_ * D_; i += 256) {
    int j = i & 7, l = (i >> 3) & 63, cg = (i >> 9) & 7, ks = i >> 12;
    int k = ks * 32 + (l >> 4) * 8 + j;
    int n = cg * 16 + (l & 15);
    out[i] = f2bf(Wr[k * D_ + n]);
  }
}

__global__ __launch_bounds__(256) void k_cast(const float* __restrict__ x, ushort* __restrict__ xb, int n8) {
  int i = blockIdx.x * 256 + threadIdx.x;
  if (i >= n8) return;
  const float4* xp = (const float4*)(x + (size_t)i * 8);
  float4 a = xp[0], b = xp[1];
  uint4 pk;
  pk.x = (uint)f2bf(a.x) | ((uint)f2bf(a.y) << 16);
  pk.y = (uint)f2bf(a.z) | ((uint)f2bf(a.w) << 16);
  pk.z = (uint)f2bf(b.x) | ((uint)f2bf(b.y) << 16);
  pk.w = (uint)f2bf(b.z) | ((uint)f2bf(b.w) << 16);
  *(uint4*)(xb + (size_t)i * 8) = pk;
}

// ---------------- y = x @ root + bias (MFMA, LDS-resident W) ----------------

__global__ __launch_bounds__(256, 4) void k_root_mfma(
    const ushort* __restrict__ xb, const ushort* __restrict__ rootPack,
    const float* __restrict__ bias, float* __restrict__ y, int nt) {
  __shared__ ushort Wl[D_ * D_];   // 32 KB
  int tstart = blockIdx.x * RG_;
  if (tstart >= nt) return;
  int tend = tstart + RG_; if (tend > nt) tend = nt;
  int w = threadIdx.x >> 6, l = threadIdx.x & 63;
  int q = l >> 4, tx = l & 15;
  {
    const uint4* wp = (const uint4*)rootPack;
    uint4* wl = (uint4*)Wl;
#pragma unroll
    for (int i = 0; i < 8; ++i) wl[i * 256 + threadIdx.x] = wp[i * 256 + threadIdx.x];
  }
  float bv[8];
#pragma unroll
  for (int cg = 0; cg < 8; ++cg) bv[cg] = bias[cg * 16 + tx];
  s8b a0, a1, a2, a3;
  {
    int gr = tstart * TE + 16 * w + tx; if (gr >= N_) gr = N_ - 1;
    const s8b* xr = (const s8b*)(xb + (size_t)gr * D_);
    a0 = xr[q]; a1 = xr[4 + q]; a2 = xr[8 + q]; a3 = xr[12 + q];
  }
  __syncthreads();
  for (int tile = tstart; tile < tend; ++tile) {
    int base = tile * TE;
    s8b n0, n1, n2, n3;
    bool pre = (tile + 1 < tend);
    if (pre) {
      int gr = base + TE + 16 * w + tx; if (gr >= N_) gr = N_ - 1;
      const s8b* xn = (const s8b*)(xb + (size_t)gr * D_);
      n0 = xn[q]; n1 = xn[4 + q]; n2 = xn[8 + q]; n3 = xn[12 + q];
    }
    f32x4 acc[8];
#pragma unroll
    for (int cg = 0; cg < 8; ++cg) acc[cg] = (f32x4){0.f, 0.f, 0.f, 0.f};
#pragma unroll
    for (int cg = 0; cg < 8; ++cg) {
      s8b b0 = *(const s8b*)&Wl[((0 * 8 + cg) * 64 + l) * 8];
      s8b b1 = *(const s8b*)&Wl[((1 * 8 + cg) * 64 + l) * 8];
      s8b b2 = *(const s8b*)&Wl[((2 * 8 + cg) * 64 + l) * 8];
      s8b b3 = *(const s8b*)&Wl[((3 * 8 + cg) * 64 + l) * 8];
      acc[cg] = __builtin_amdgcn_mfma_f32_16x16x32_bf16(a0, b0, acc[cg], 0, 0, 0);
      acc[cg] = __builtin_amdgcn_mfma_f32_16x16x32_bf16(a1, b1, acc[cg], 0, 0, 0);
      acc[cg] = __builtin_amdgcn_mfma_f32_16x16x32_bf16(a2, b2, acc[cg], 0, 0, 0);
      acc[cg] = __builtin_amdgcn_mfma_f32_16x16x32_bf16(a3, b3, acc[cg], 0, 0, 0);
    }
#pragma unroll
    for (int cg = 0; cg < 8; ++cg)
#pragma unroll
      for (int r = 0; r < 4; ++r) {
        int gr = base + 16 * w + 4 * q + r;
        if (gr < N_) y[(size_t)gr * D_ + cg * 16 + tx] = acc[cg][r] + bv[cg];
      }
    if (pre) { a0 = n0; a1 = n1; a2 = n2; a3 = n3; }
  }
}

// ---------------- phase A: MFMA edge messages ----------------
// LDS-resident W + wave-private staging tile for full-128B-line msg stores.

__global__ __launch_bounds__(256, 4) void k_edges_mfma(
    const ushort* __restrict__ xb, const ushort* __restrict__ Wpack,
    const int2* __restrict__ srcdst, const float* __restrict__ normS,
    const int* __restrict__ tileRel, const int* __restrict__ padOff,
    ushort* __restrict__ msg, int tile0, int tile1, int G) {
  __shared__ ushort Wl[D_ * D_];        // 32 KB, one relation
  __shared__ ushort stg[4][16 * 136];   // 17 KB, wave-private staging (pad 136)
  int padTot = padOff[R_];
  int w = threadIdx.x >> 6, l = threadIdx.x & 63;
  int q = l >> 4, tx = l & 15;
  int g = l >> 3, m = l & 7;
  ushort* st = stg[w];
  int curRel = -1;
  for (int tb = tile0 + blockIdx.x * G; tb < tile1; tb += gridDim.x * G) {
    if (tb * TE >= padTot) break;
    int tend = tb + G; if (tend > tile1) tend = tile1;
    s8b a0, a1, a2, a3;
    {
      int2 sd = srcdst[tb * TE + 16 * w + tx];
      int sr = sd.x < 0 ? 0 : sd.x;
      const s8b* xr = (const s8b*)(xb + (size_t)sr * D_);
      a0 = xr[q]; a1 = xr[4 + q]; a2 = xr[8 + q]; a3 = xr[12 + q];
    }
    for (int tile = tb; tile < tend; ++tile) {
      int base = tile * TE;
      if (base >= padTot) break;
      int rel = tileRel[tile];
      if (rel != curRel) {                    // block-uniform branch
        curRel = rel;
        __syncthreads();
        const uint4* wp = (const uint4*)(Wpack + (size_t)rel * (D_ * D_));
        uint4* wl = (uint4*)Wl;
#pragma unroll
        for (int i = 0; i < 8; ++i) wl[i * 256 + threadIdx.x] = wp[i * 256 + threadIdx.x];
        __syncthreads();
      }
      float nv[4];
#pragma unroll
      for (int r = 0; r < 4; ++r) nv[r] = normS[base + 16 * w + 4 * q + r];
      // prefetch next tile's A fragments
      s8b n0, n1, n2, n3;
      int nb = base + TE;
      bool pre = (tile + 1 < tend) && (nb < padTot);
      if (pre) {
        int2 sd = srcdst[nb + 16 * w + tx];
        int sr = sd.x < 0 ? 0 : sd.x;
        const s8b* xn = (const s8b*)(xb + (size_t)sr * D_);
        n0 = xn[q]; n1 = xn[4 + q]; n2 = xn[8 + q]; n3 = xn[12 + q];
      }
      f32x4 acc[8];
#pragma unroll
      for (int cg = 0; cg < 8; ++cg) acc[cg] = (f32x4){0.f, 0.f, 0.f, 0.f};
#pragma unroll
      for (int cg = 0; cg < 8; ++cg) {
        s8b b0 = *(const s8b*)&Wl[((0 * 8 + cg) * 64 + l) * 8];
        s8b b1 = *(const s8b*)&Wl[((1 * 8 + cg) * 64 + l) * 8];
        s8b b2 = *(const s8b*)&Wl[((2 * 8 + cg) * 64 + l) * 8];
        s8b b3 = *(const s8b*)&Wl[((3 * 8 + cg) * 64 + l) * 8];
        acc[cg] = __builtin_amdgcn_mfma_f32_16x16x32_bf16(a0, b0, acc[cg], 0, 0, 0);
        acc[cg] = __builtin_amdgcn_mfma_f32_16x16x32_bf16(a1, b1, acc[cg], 0, 0, 0);
        acc[cg] = __builtin_amdgcn_mfma_f32_16x16x32_bf16(a2, b2, acc[cg], 0, 0, 0);
        acc[cg] = __builtin_amdgcn_mfma_f32_16x16x32_bf16(a3, b3, acc[cg], 0, 0, 0);
      }
      // stage to wave-private LDS (no barrier; in-wave lgkmcnt ordering)
#pragma unroll
      for (int cg = 0; cg < 8; ++cg)
#pragma unroll
        for (int r = 0; r < 4; ++r)
          st[(4 * q + r) * 136 + cg * 16 + tx] = f2bf(acc[cg][r] * nv[r]);
      // write back as full 128B lines: 4 instrs, each 8 rows x 128B aligned
      ushort* mbase = msg + (size_t)(base - tile0 * TE + 16 * w) * D_;
#pragma unroll
      for (int jj = 0; jj < 2; ++jj)
#pragma unroll
        for (int hh = 0; hh < 2; ++hh) {
          int row = 8 * jj + g;
          u32x4 v = *(const u32x4*)&st[row * 136 + hh * 64 + m * 8];
          *(u32x4*)(mbase + (size_t)row * D_ + hh * 64 + m * 8) = v;
        }
      if (pre) { a0 = n0; a1 = n1; a2 = n2; a3 = n3; }
    }
  }
}

// ---------------- phase B: wave-per-dst aggregation ----------------
// mode 0: RMW fp32 y.  mode 1: final layer-2 (relu, fp32 y).  mode 2: final layer-1 (relu, write bf16 xb).

__global__ __launch_bounds__(256) void k_agg2(const ushort* __restrict__ msg, const int* __restrict__ posbuf,
                                              const int* __restrict__ jlo, const int* __restrict__ jhi,
                                              float* __restrict__ y, ushort* __restrict__ xbOut,
                                              int plo, int mode) {
  int d = blockIdx.x * 4 + (threadIdx.x >> 6);
  if (d >= N_) return;
  int l = threadIdx.x & 63, sub = l >> 4, tx = l & 15;
  int s0 = jlo[d], s1 = jhi[d];
  float acc[8];
#pragma unroll
  for (int i = 0; i < 8; ++i) acc[i] = 0.f;
  for (int j = s0 + sub; j < s1; j += 4) {
    int p = posbuf[j];
    u32x4 mv = *(const u32x4*)(msg + (((size_t)(p - plo)) << 7) + (tx << 3));
    acc[0] += bf2f((ushort)mv[0]); acc[1] += bf2f((ushort)(mv[0] >> 16));
    acc[2] += bf2f((ushort)mv[1]); acc[3] += bf2f((ushort)(mv[1] >> 16));
    acc[4] += bf2f((ushort)mv[2]); acc[5] += bf2f((ushort)(mv[2] >> 16));
    acc[6] += bf2f((ushort)mv[3]); acc[7] += bf2f((ushort)(mv[3] >> 16));
  }
#pragma unroll
  for (int i = 0; i < 8; ++i) {
    acc[i] += __shfl_xor(acc[i], 16);
    acc[i] += __shfl_xor(acc[i], 32);
  }
  if (sub == 0) {
    float* yp = y + (((size_t)d) << 7) + (tx << 3);
    float4 y0 = *(float4*)yp, y1 = *(float4*)(yp + 4);
    y0.x += acc[0]; y0.y += acc[1]; y0.z += acc[2]; y0.w += acc[3];
    y1.x += acc[4]; y1.y += acc[5]; y1.z += acc[6]; y1.w += acc[7];
    if (mode == 0) {
      *(float4*)yp = y0; *(float4*)(yp + 4) = y1;
    } else {
      y0.x = fmaxf(y0.x, 0.f); y0.y = fmaxf(y0.y, 0.f); y0.z = fmaxf(y0.z, 0.f); y0.w = fmaxf(y0.w, 0.f);
      y1.x = fmaxf(y1.x, 0.f); y1.y = fmaxf(y1.y, 0.f); y1.z = fmaxf(y1.z, 0.f); y1.w = fmaxf(y1.w, 0.f);
      if (mode == 1) {
        *(float4*)yp = y0; *(float4*)(yp + 4) = y1;
      } else {
        uint4 pk;
        pk.x = (uint)f2bf(y0.x) | ((uint)f2bf(y0.y) << 16);
        pk.y = (uint)f2bf(y0.z) | ((uint)f2bf(y0.w) << 16);
        pk.z = (uint)f2bf(y1.x) | ((uint)f2bf(y1.y) << 16);
        pk.w = (uint)f2bf(y1.z) | ((uint)f2bf(y1.w) << 16);
        *(uint4*)(xbOut + (((size_t)d) << 7) + (tx << 3)) = pk;
      }
    }
  }
}

// ---------------- launch ----------------

extern "C" void kernel_launch(void* const* d_in, const int* in_sizes, int n_in,
                              void* d_out, int out_size, void* d_ws, size_t ws_size,
                              hipStream_t stream) {
  const float* entity = (const float*)d_in[0];
  const float* comp   = (const float*)d_in[1];
  const float* basis  = (const float*)d_in[2];
  const float* root   = (const float*)d_in[3];
  const float* bias   = (const float*)d_in[4];
  const int*   eidx   = (const int*)d_in[5];
  const int*   etype  = (const int*)d_in[6];
  const int E = in_sizes[6];
  const int* src = eidx;
  const int* dst = eidx + E;

  char* ws = (char*)d_ws;
  const size_t Epad = (size_t)E + (size_t)R_ * TE;
  const int uTiles = (E + TE - 1) / TE + R_;
  const int NBLK = (N_ + 1 + 255) / 256;
  auto al = [](size_t x) { return (x + 255) & ~(size_t)255; };

  size_t o_Wpack  = 0;
  size_t o_srcdst = al(o_Wpack + (size_t)(R_ + 1) * D_ * D_ * 2);   // +1 slot for packed root
  size_t o_normS  = al(o_srcdst + Epad * 8);
  size_t o_posbuf = al(o_normS + Epad * 4);
  size_t o_degDst = al(o_posbuf + (size_t)E * 4);
  size_t o_dstOff = al(o_degDst + (size_t)N_ * 4);
  size_t o_cursD  = al(o_dstOff + (size_t)(N_ + 8) * 4);
  size_t o_bounds = al(o_cursD + (size_t)N_ * 4);
  size_t o_tileRel= al(o_bounds + (size_t)MAXC * N_ * 4);
  size_t o_small  = al(o_tileRel + (size_t)uTiles * 4);
  size_t o_y1     = al(o_small + 8192);
  size_t o_xb     = al(o_y1 + (size_t)N_ * D_ * 4);
  size_t o_msg    = al(o_xb + (size_t)N_ * D_ * 2);

  // alias inside the msg region (dead before first msg write):
  size_t o_Wf     = o_msg;                 // per-layer, dead after k_packW (before msg writes)

  ushort* Wpack  = (ushort*)(ws + o_Wpack);
  int2*   srcdst = (int2*)(ws + o_srcdst);
  float*  normS  = (float*)(ws + o_normS);
  int*    posbuf = (int*)(ws + o_posbuf);
  int*    degDst = (int*)(ws + o_degDst);
  int*    dstOff = (int*)(ws + o_dstOff);
  int*    cursD  = (int*)(ws + o_cursD);
  int*    bounds = (int*)(ws + o_bounds);
  int*    tileRel= (int*)(ws + o_tileRel);
  int*    hist   = (int*)(ws + o_small);
  int*    padOff = hist + 256;
  int*    cursor = hist + 512;
  int*    blkSum = hist + 768;
  int*    blkOff = hist + 1280;
  float*  y1     = (float*)(ws + o_y1);
  ushort* xb     = (ushort*)(ws + o_xb);
  float*  Wf     = (float*)(ws + o_Wf);
  ushort* msg    = (ushort*)(ws + o_msg);
  ushort* rootPack = Wpack + (size_t)R_ * D_ * D_;

  (void)hipMemsetAsync(ws + o_srcdst, 0xFF, Epad * 8, stream);   // padding: src=dst=-1
  (void)hipMemsetAsync(ws + o_degDst, 0, (size_t)N_ * 4, stream);
  (void)hipMemsetAsync(ws + o_small, 0, 8192, stream);

  int gH = (E + 4095) / 4096;
  k_hist<<<gH, 256, 0, stream>>>(etype, E, hist);
  k_scanRel<<<1, 256, 0, stream>>>(hist, padOff, cursor);
  k_scatter<<<gH, 256, 0, stream>>>(src, dst, etype, E, cursor, srcdst, degDst);
  k_tileRel<<<(uTiles + 255) / 256, 256, 0, stream>>>(padOff, tileRel, uTiles);
  k_degPart<<<NBLK, 256, 0, stream>>>(degDst, blkSum);
  k_scanBlk<<<1, 512, 0, stream>>>(blkSum, blkOff, NBLK);
  k_writeOff<<<NBLK, 256, 0, stream>>>(degDst, blkOff, dstOff, cursD);

  // chunking: ws capacity AND L3-residency target (~136MB per chunk -> nch=3)
  size_t cap = (ws_size > o_msg + 16384) ? (ws_size - o_msg) : (size_t)16384;
  size_t tileBytes = (size_t)TE * D_ * 2;
  long long maxT = (long long)(cap / tileBytes);
  if (maxT < 1) maxT = 1;
  int nch = (int)((uTiles + maxT - 1) / maxT);
  if (nch < 1) nch = 1;
  size_t totalMsg = (size_t)uTiles * tileBytes;
  int nchT = (int)((totalMsg + ((size_t)136 << 20) - 1) / ((size_t)136 << 20));
  if (nch < nchT) nch = nchT;
  if (nch > MAXC) nch = MAXC;
  int chunkTiles = (uTiles + nch - 1) / nch;
  nch = (uTiles + chunkTiles - 1) / chunkTiles;

  // chunk-major posbuf: scatter per chunk, snapshot cursors
  for (int c = 0; c < nch; c++) {
    int plo = c * chunkTiles * TE;
    int phi = (c + 1) * chunkTiles * TE; if (phi > uTiles * TE) phi = uTiles * TE;
    int gS = (phi - plo + 255) / 256;
    if (gS > 0)
      k_scatterDst<<<gS, 256, 0, stream>>>(srcdst, padOff, cursD, posbuf, plo, phi);
    k_copyBound<<<(N_ + 255) / 256, 256, 0, stream>>>(cursD, bounds + (size_t)c * N_);
  }

  k_norm<<<(N_ + 3) / 4, 256, 0, stream>>>(posbuf, dstOff, tileRel, normS);

  int ntR = (N_ + TE - 1) / TE;
  int gAgg = (N_ + 3) / 4;
  k_cast<<<(N_ * D_ / 8 + 255) / 256, 256, 0, stream>>>(entity, xb, N_ * D_ / 8);
  for (int l = 0; l < 2; l++) {
    float* yout = l ? (float*)d_out : y1;
    k_computeW<<<R_ * 64, 256, 0, stream>>>(comp + l * R_ * B_, basis + (size_t)l * B_ * D_ * D_, Wf);
    k_packW<<<R_, 256, 0, stream>>>(Wf, Wpack);
    k_packW<<<1, 256, 0, stream>>>(root + (size_t)l * D_ * D_, rootPack);
    k_root_mfma<<<(ntR + RG_ - 1) / RG_, 256, 0, stream>>>(xb, rootPack, bias + l * D_, yout, ntR);
    for (int c = 0; c < nch; c++) {
      int t0 = c * chunkTiles;
      int t1 = t0 + chunkTiles; if (t1 > uTiles) t1 = uTiles;
      int tiles = t1 - t0;
      int G = (tiles + 1023) / 1024; if (G < 4) G = 4;
      int gB = (tiles + G - 1) / G;
      k_edges_mfma<<<gB, 256, 0, stream>>>(xb, Wpack, srcdst, normS, tileRel, padOff, msg, t0, t1, G);
      const int* jlo = (c == 0) ? dstOff : bounds + (size_t)(c - 1) * N_;
      const int* jhi = bounds + (size_t)c * N_;
      int mode = (c == nch - 1) ? (l ? 1 : 2) : 0;
      k_agg2<<<gAgg, 256, 0, stream>>>(msg, posbuf, jlo, jhi, yout, xb, t0 * TE, mode);
    }
  }
}

// Round 11
// 1040.453 us; speedup vs baseline: 1.7382x; 1.1113x over previous
//
#include <hip/hip_runtime.h>
#include <hip/hip_bf16.h>
#include <stdint.h>

#define D_ 128
#define R_ 200
#define B_ 50
#define N_ 100000
#define TE 64
#define RG_ 4
#define MAXC 8

typedef __attribute__((ext_vector_type(8))) short s8b;
typedef __attribute__((ext_vector_type(4))) float f32x4;
typedef __attribute__((ext_vector_type(4))) uint u32x4;

// ---------------- helpers ----------------

__device__ __forceinline__ ushort f2bf(float f) {   // RTN-even fp32 -> bf16
  uint u = __float_as_uint(f);
  return (ushort)((u + 0x7fffu + ((u >> 16) & 1u)) >> 16);
}
__device__ __forceinline__ float bf2f(ushort u) {
  return __uint_as_float(((uint)u) << 16);
}

// ---------------- counting / sorting machinery ----------------

__global__ __launch_bounds__(256) void k_hist(const int* __restrict__ et, int E, int* __restrict__ hist) {
  __shared__ int h[R_];
  for (int i = threadIdx.x; i < R_; i += 256) h[i] = 0;
  __syncthreads();
  int base = blockIdx.x * 4096;
  for (int j = 0; j < 16; j++) {
    int i = base + j * 256 + threadIdx.x;
    if (i < E) atomicAdd(&h[et[i]], 1);
  }
  __syncthreads();
  for (int i = threadIdx.x; i < R_; i += 256) { int v = h[i]; if (v) atomicAdd(&hist[i], v); }
}

// parallel relation scan with TE-padding (1 block, 256 threads)
__global__ __launch_bounds__(256) void k_scanRel(const int* __restrict__ hist,
                                                 int* __restrict__ padOff, int* __restrict__ cursor) {
  __shared__ int s[256];
  int tid = threadIdx.x;
  int v = (tid < R_) ? ((hist[tid] + TE - 1) / TE) * TE : 0;
  s[tid] = v;
  __syncthreads();
  for (int off = 1; off < 256; off <<= 1) {
    int t = (tid >= off) ? s[tid - off] : 0;
    __syncthreads();
    s[tid] += t;
    __syncthreads();
  }
  if (tid < R_) { int e = s[tid] - v; padOff[tid] = e; cursor[tid] = e; }
  if (tid == R_ - 1) padOff[R_] = s[tid];
}

// relation-sort scatter + dst-degree count fused (one pass over edges)
__global__ __launch_bounds__(256) void k_scatter(const int* __restrict__ src, const int* __restrict__ dst,
                                                 const int* __restrict__ et, int E,
                                                 int* __restrict__ cursor,
                                                 int2* __restrict__ srcdst, int* __restrict__ deg) {
  __shared__ int h[R_];
  __shared__ int gb[R_];
  for (int i = threadIdx.x; i < R_; i += 256) h[i] = 0;
  __syncthreads();
  int base = blockIdx.x * 4096;
  int lrank[16];
#pragma unroll
  for (int j = 0; j < 16; j++) {
    int i = base + j * 256 + threadIdx.x;
    lrank[j] = (i < E) ? atomicAdd(&h[et[i]], 1) : 0;
  }
  __syncthreads();
  for (int i = threadIdx.x; i < R_; i += 256) { int v = h[i]; gb[i] = v ? atomicAdd(&cursor[i], v) : 0; }
  __syncthreads();
#pragma unroll
  for (int j = 0; j < 16; j++) {
    int i = base + j * 256 + threadIdx.x;
    if (i < E) {
      int r = et[i], d = dst[i];
      int pos = gb[r] + lrank[j];
      int2 sd; sd.x = src[i]; sd.y = d;
      srcdst[pos] = sd;
      atomicAdd(&deg[d], 1);
    }
  }
}

__global__ __launch_bounds__(256) void k_tileRel(const int* __restrict__ padOff, int* __restrict__ tileRel, int uT) {
  int t = blockIdx.x * 256 + threadIdx.x;
  if (t >= uT) return;
  int base = t * TE;
  if (base >= padOff[R_]) { tileRel[t] = 0; return; }
  int lo = 0, hi = R_ - 1;
  while (lo < hi) { int mid = (lo + hi + 1) >> 1; if (padOff[mid] <= base) lo = mid; else hi = mid - 1; }
  tileRel[t] = lo;
}

// ---------------- dst-sort: parallel 3-kernel scan ----------------

__global__ __launch_bounds__(256) void k_degPart(const int* __restrict__ deg, int* __restrict__ blkSum) {
  __shared__ int ws_[4];
  int i = blockIdx.x * 256 + threadIdx.x;
  int v = (i < N_) ? deg[i] : 0;
#pragma unroll
  for (int off = 32; off >= 1; off >>= 1) v += __shfl_down(v, off);
  if ((threadIdx.x & 63) == 0) ws_[threadIdx.x >> 6] = v;
  __syncthreads();
  if (threadIdx.x == 0) blkSum[blockIdx.x] = ws_[0] + ws_[1] + ws_[2] + ws_[3];
}

__global__ __launch_bounds__(512) void k_scanBlk(const int* __restrict__ blkSum, int* __restrict__ blkOff, int nblk) {
  __shared__ int s[512];
  int tid = threadIdx.x;
  int v = (tid < nblk) ? blkSum[tid] : 0;
  s[tid] = v;
  __syncthreads();
  for (int off = 1; off < 512; off <<= 1) {
    int t = (tid >= off) ? s[tid - off] : 0;
    __syncthreads();
    s[tid] += t;
    __syncthreads();
  }
  if (tid < nblk) blkOff[tid] = s[tid] - v;   // exclusive
}

__global__ __launch_bounds__(256) void k_writeOff(const int* __restrict__ deg, const int* __restrict__ blkOff,
                                                  int* __restrict__ dstOff, int* __restrict__ cur) {
  __shared__ int s[256];
  int i = blockIdx.x * 256 + threadIdx.x;
  int tid = threadIdx.x;
  int v = (i < N_) ? deg[i] : 0;
  s[tid] = v;
  __syncthreads();
  for (int off = 1; off < 256; off <<= 1) {
    int t = (tid >= off) ? s[tid - off] : 0;
    __syncthreads();
    s[tid] += t;
    __syncthreads();
  }
  int e = blkOff[blockIdx.x] + s[tid] - v;    // global exclusive prefix
  if (i < N_) { dstOff[i] = e; cur[i] = e; }
  else if (i == N_) dstOff[N_] = e;
}

__global__ __launch_bounds__(256) void k_scatterDst(const int2* __restrict__ srcdst,
                                                    const int* __restrict__ padOff, int* __restrict__ cur,
                                                    int* __restrict__ posbuf, int plo, int phi) {
  int p = plo + blockIdx.x * 256 + threadIdx.x;
  if (p >= phi || p >= padOff[R_]) return;
  int d = srcdst[p].y;
  if (d < 0) return;                 // padding slot
  int j = atomicAdd(&cur[d], 1);
  posbuf[j] = p;
}

__global__ __launch_bounds__(256) void k_copyBound(const int* __restrict__ cur, int* __restrict__ bnd) {
  int d = blockIdx.x * 256 + threadIdx.x;
  if (d < N_) bnd[d] = cur[d];
}

// ---------------- per-edge mean-norm from dst-sorted segments ----------------

__global__ __launch_bounds__(256) void k_norm(const int* __restrict__ posbuf, const int* __restrict__ dstOff,
                                              const int* __restrict__ tileRel, float* __restrict__ normS) {
  __shared__ int rels[4][128];
  int d = blockIdx.x * 4 + (threadIdx.x >> 6);
  int sub = threadIdx.x >> 6;
  int l = threadIdx.x & 63;
  int s0 = 0, deg = 0;
  if (d < N_) { s0 = dstOff[d]; deg = dstOff[d + 1] - s0; }
  int cap = deg < 128 ? deg : 128;
  int myp[4]; int myr[4];
  for (int j = l, t = 0; j < cap; j += 64, ++t) {
    int p = posbuf[s0 + j];
    int r = tileRel[p >> 6];
    rels[sub][j] = r;
    if (t < 4) { myp[t] = p; myr[t] = r; }
  }
  __syncthreads();
  if (d >= N_) return;
  for (int j = l, t = 0; j < deg; j += 64, ++t) {
    int p, r;
    if (j < 128 && t < 4) { p = myp[t]; r = myr[t]; }
    else { p = posbuf[s0 + j]; r = tileRel[p >> 6]; }
    int cnt = 0;
    for (int k = 0; k < deg; k++) {
      int rk = (k < 128) ? rels[sub][k] : tileRel[posbuf[s0 + k] >> 6];
      cnt += (rk == r) ? 1 : 0;
    }
    normS[p] = 1.0f / (float)(cnt > 0 ? cnt : 1);
  }
}

// ---------------- W_r = sum_b comp[r,b]*basis[b]; pack to B-fragment order ----------------

__global__ __launch_bounds__(256) void k_computeW(const float* __restrict__ comp, const float* __restrict__ basis,
                                                  float* __restrict__ W) {
  __shared__ float c[B_];
  int r = blockIdx.x >> 6;
  int chunk = blockIdx.x & 63;
  if (threadIdx.x < B_) c[threadIdx.x] = comp[r * B_ + threadIdx.x];
  __syncthreads();
  int ij = chunk * 256 + threadIdx.x;
  float acc = 0.f;
#pragma unroll 10
  for (int b = 0; b < B_; b++) acc += c[b] * basis[b * (D_ * D_) + ij];
  W[r * (D_ * D_) + ij] = acc;
}

// pack: Wpack[r][ks][cg][lane][j] = bf16(W[r][ks*32+(lane>>4)*8+j][cg*16+(lane&15)])
__global__ __launch_bounds__(256) void k_packW(const float* __restrict__ W, ushort* __restrict__ Wpack) {
  int r = blockIdx.x;
  const float* Wr = W + (size_t)r * (D_ * D_);
  ushort* out = Wpack + (size_t)r * (D_ * D_);
  for (int i = threadIdx.x; i < D_ * D_; i += 256) {
    int j = i & 7, l = (i >> 3) & 63, cg = (i >> 9) & 7, ks = i >> 12;
    int k = ks * 32 + (l >> 4) * 8 + j;
    int n = cg * 16 + (l & 15);
    out[i] = f2bf(Wr[k * D_ + n]);
  }
}

__global__ __launch_bounds__(256) void k_cast(const float* __restrict__ x, ushort* __restrict__ xb, int n8) {
  int i = blockIdx.x * 256 + threadIdx.x;
  if (i >= n8) return;
  const float4* xp = (const float4*)(x + (size_t)i * 8);
  float4 a = xp[0], b = xp[1];
  uint4 pk;
  pk.x = (uint)f2bf(a.x) | ((uint)f2bf(a.y) << 16);
  pk.y = (uint)f2bf(a.z) | ((uint)f2bf(a.w) << 16);
  pk.z = (uint)f2bf(b.x) | ((uint)f2bf(b.y) << 16);
  pk.w = (uint)f2bf(b.z) | ((uint)f2bf(b.w) << 16);
  *(uint4*)(xb + (size_t)i * 8) = pk;
}

// ---------------- y = x @ root + bias (MFMA, LDS-resident W, full-line stores) ----------------

__global__ __launch_bounds__(256, 2) void k_root_mfma(
    const ushort* __restrict__ xb, const ushort* __restrict__ rootPack,
    const float* __restrict__ bias, float* __restrict__ y, int nt) {
  __shared__ ushort Wl[D_ * D_];        // 32 KB
  __shared__ float stg[4][16 * 132];    // 33.8 KB, wave-private fp32 staging
  int tstart = blockIdx.x * RG_;
  if (tstart >= nt) return;
  int tend = tstart + RG_; if (tend > nt) tend = nt;
  int w = threadIdx.x >> 6, l = threadIdx.x & 63;
  int q = l >> 4, tx = l & 15;
  int half = l >> 5, l32 = l & 31;
  float* st = stg[w];
  {
    const uint4* wp = (const uint4*)rootPack;
    uint4* wl = (uint4*)Wl;
#pragma unroll
    for (int i = 0; i < 8; ++i) wl[i * 256 + threadIdx.x] = wp[i * 256 + threadIdx.x];
  }
  float bv[8];
#pragma unroll
  for (int cg = 0; cg < 8; ++cg) bv[cg] = bias[cg * 16 + tx];
  s8b a0, a1, a2, a3;
  {
    int gr = tstart * TE + 16 * w + tx; if (gr >= N_) gr = N_ - 1;
    const s8b* xr = (const s8b*)(xb + (size_t)gr * D_);
    a0 = xr[q]; a1 = xr[4 + q]; a2 = xr[8 + q]; a3 = xr[12 + q];
  }
  __syncthreads();
  for (int tile = tstart; tile < tend; ++tile) {
    int base = tile * TE;
    s8b n0, n1, n2, n3;
    bool pre = (tile + 1 < tend);
    if (pre) {
      int gr = base + TE + 16 * w + tx; if (gr >= N_) gr = N_ - 1;
      const s8b* xn = (const s8b*)(xb + (size_t)gr * D_);
      n0 = xn[q]; n1 = xn[4 + q]; n2 = xn[8 + q]; n3 = xn[12 + q];
    }
    f32x4 acc[8];
#pragma unroll
    for (int cg = 0; cg < 8; ++cg) acc[cg] = (f32x4){0.f, 0.f, 0.f, 0.f};
#pragma unroll
    for (int cg = 0; cg < 8; ++cg) {
      s8b b0 = *(const s8b*)&Wl[((0 * 8 + cg) * 64 + l) * 8];
      s8b b1 = *(const s8b*)&Wl[((1 * 8 + cg) * 64 + l) * 8];
      s8b b2 = *(const s8b*)&Wl[((2 * 8 + cg) * 64 + l) * 8];
      s8b b3 = *(const s8b*)&Wl[((3 * 8 + cg) * 64 + l) * 8];
      acc[cg] = __builtin_amdgcn_mfma_f32_16x16x32_bf16(a0, b0, acc[cg], 0, 0, 0);
      acc[cg] = __builtin_amdgcn_mfma_f32_16x16x32_bf16(a1, b1, acc[cg], 0, 0, 0);
      acc[cg] = __builtin_amdgcn_mfma_f32_16x16x32_bf16(a2, b2, acc[cg], 0, 0, 0);
      acc[cg] = __builtin_amdgcn_mfma_f32_16x16x32_bf16(a3, b3, acc[cg], 0, 0, 0);
    }
    // stage to wave-private LDS (fp32, no barrier)
#pragma unroll
    for (int cg = 0; cg < 8; ++cg)
#pragma unroll
      for (int r = 0; r < 4; ++r)
        st[(4 * q + r) * 132 + cg * 16 + tx] = acc[cg][r] + bv[cg];
    // write back: each instr = 2 rows x 512B contiguous = full 128B lines
    int grBase = base + 16 * w;
#pragma unroll
    for (int k = 0; k < 8; ++k) {
      int row = 2 * k + half;
      int gr = grBase + row;
      f32x4 v = *(const f32x4*)&st[row * 132 + l32 * 4];
      if (gr < N_) *(f32x4*)(y + (size_t)gr * D_ + l32 * 4) = v;
    }
    if (pre) { a0 = n0; a1 = n1; a2 = n2; a3 = n3; }
  }
}

// ---------------- phase A: MFMA edge messages ----------------
// LDS-resident W + wave-private staging tile for full-128B-line msg stores.

__global__ __launch_bounds__(256, 4) void k_edges_mfma(
    const ushort* __restrict__ xb, const ushort* __restrict__ Wpack,
    const int2* __restrict__ srcdst, const float* __restrict__ normS,
    const int* __restrict__ tileRel, const int* __restrict__ padOff,
    ushort* __restrict__ msg, int tile0, int tile1, int G) {
  __shared__ ushort Wl[D_ * D_];        // 32 KB, one relation
  __shared__ ushort stg[4][16 * 136];   // 17 KB, wave-private staging (pad 136)
  int padTot = padOff[R_];
  int w = threadIdx.x >> 6, l = threadIdx.x & 63;
  int q = l >> 4, tx = l & 15;
  int g = l >> 3, m = l & 7;
  ushort* st = stg[w];
  int curRel = -1;
  for (int tb = tile0 + blockIdx.x * G; tb < tile1; tb += gridDim.x * G) {
    if (tb * TE >= padTot) break;
    int tend = tb + G; if (tend > tile1) tend = tile1;
    s8b a0, a1, a2, a3;
    {
      int2 sd = srcdst[tb * TE + 16 * w + tx];
      int sr = sd.x < 0 ? 0 : sd.x;
      const s8b* xr = (const s8b*)(xb + (size_t)sr * D_);
      a0 = xr[q]; a1 = xr[4 + q]; a2 = xr[8 + q]; a3 = xr[12 + q];
    }
    for (int tile = tb; tile < tend; ++tile) {
      int base = tile * TE;
      if (base >= padTot) break;
      int rel = tileRel[tile];
      if (rel != curRel) {                    // block-uniform branch
        curRel = rel;
        __syncthreads();
        const uint4* wp = (const uint4*)(Wpack + (size_t)rel * (D_ * D_));
        uint4* wl = (uint4*)Wl;
#pragma unroll
        for (int i = 0; i < 8; ++i) wl[i * 256 + threadIdx.x] = wp[i * 256 + threadIdx.x];
        __syncthreads();
      }
      float nv[4];
#pragma unroll
      for (int r = 0; r < 4; ++r) nv[r] = normS[base + 16 * w + 4 * q + r];
      // prefetch next tile's A fragments
      s8b n0, n1, n2, n3;
      int nb = base + TE;
      bool pre = (tile + 1 < tend) && (nb < padTot);
      if (pre) {
        int2 sd = srcdst[nb + 16 * w + tx];
        int sr = sd.x < 0 ? 0 : sd.x;
        const s8b* xn = (const s8b*)(xb + (size_t)sr * D_);
        n0 = xn[q]; n1 = xn[4 + q]; n2 = xn[8 + q]; n3 = xn[12 + q];
      }
      f32x4 acc[8];
#pragma unroll
      for (int cg = 0; cg < 8; ++cg) acc[cg] = (f32x4){0.f, 0.f, 0.f, 0.f};
#pragma unroll
      for (int cg = 0; cg < 8; ++cg) {
        s8b b0 = *(const s8b*)&Wl[((0 * 8 + cg) * 64 + l) * 8];
        s8b b1 = *(const s8b*)&Wl[((1 * 8 + cg) * 64 + l) * 8];
        s8b b2 = *(const s8b*)&Wl[((2 * 8 + cg) * 64 + l) * 8];
        s8b b3 = *(const s8b*)&Wl[((3 * 8 + cg) * 64 + l) * 8];
        acc[cg] = __builtin_amdgcn_mfma_f32_16x16x32_bf16(a0, b0, acc[cg], 0, 0, 0);
        acc[cg] = __builtin_amdgcn_mfma_f32_16x16x32_bf16(a1, b1, acc[cg], 0, 0, 0);
        acc[cg] = __builtin_amdgcn_mfma_f32_16x16x32_bf16(a2, b2, acc[cg], 0, 0, 0);
        acc[cg] = __builtin_amdgcn_mfma_f32_16x16x32_bf16(a3, b3, acc[cg], 0, 0, 0);
      }
      // stage to wave-private LDS (no barrier; in-wave lgkmcnt ordering)
#pragma unroll
      for (int cg = 0; cg < 8; ++cg)
#pragma unroll
        for (int r = 0; r < 4; ++r)
          st[(4 * q + r) * 136 + cg * 16 + tx] = f2bf(acc[cg][r] * nv[r]);
      // write back as full 128B lines: 4 instrs, each 8 rows x 128B aligned
      ushort* mbase = msg + (size_t)(base - tile0 * TE + 16 * w) * D_;
#pragma unroll
      for (int jj = 0; jj < 2; ++jj)
#pragma unroll
        for (int hh = 0; hh < 2; ++hh) {
          int row = 8 * jj + g;
          u32x4 v = *(const u32x4*)&st[row * 136 + hh * 64 + m * 8];
          *(u32x4*)(mbase + (size_t)row * D_ + hh * 64 + m * 8) = v;
        }
      if (pre) { a0 = n0; a1 = n1; a2 = n2; a3 = n3; }
    }
  }
}

// ---------------- phase B: wave-per-dst aggregation ----------------
// mode 0: RMW fp32 y.  mode 1: final layer-2 (relu, fp32 y).  mode 2: final layer-1 (relu, write bf16 xb).

__global__ __launch_bounds__(256) void k_agg2(const ushort* __restrict__ msg, const int* __restrict__ posbuf,
                                              const int* __restrict__ jlo, const int* __restrict__ jhi,
                                              float* __restrict__ y, ushort* __restrict__ xbOut,
                                              int plo, int mode) {
  int d = blockIdx.x * 4 + (threadIdx.x >> 6);
  if (d >= N_) return;
  int l = threadIdx.x & 63, sub = l >> 4, tx = l & 15;
  int s0 = jlo[d], s1 = jhi[d];
  float acc[8];
#pragma unroll
  for (int i = 0; i < 8; ++i) acc[i] = 0.f;
  for (int j = s0 + sub; j < s1; j += 4) {
    int p = posbuf[j];
    u32x4 mv = *(const u32x4*)(msg + (((size_t)(p - plo)) << 7) + (tx << 3));
    acc[0] += bf2f((ushort)mv[0]); acc[1] += bf2f((ushort)(mv[0] >> 16));
    acc[2] += bf2f((ushort)mv[1]); acc[3] += bf2f((ushort)(mv[1] >> 16));
    acc[4] += bf2f((ushort)mv[2]); acc[5] += bf2f((ushort)(mv[2] >> 16));
    acc[6] += bf2f((ushort)mv[3]); acc[7] += bf2f((ushort)(mv[3] >> 16));
  }
#pragma unroll
  for (int i = 0; i < 8; ++i) {
    acc[i] += __shfl_xor(acc[i], 16);
    acc[i] += __shfl_xor(acc[i], 32);
  }
  if (sub == 0) {
    float* yp = y + (((size_t)d) << 7) + (tx << 3);
    float4 y0 = *(float4*)yp, y1 = *(float4*)(yp + 4);
    y0.x += acc[0]; y0.y += acc[1]; y0.z += acc[2]; y0.w += acc[3];
    y1.x += acc[4]; y1.y += acc[5]; y1.z += acc[6]; y1.w += acc[7];
    if (mode == 0) {
      *(float4*)yp = y0; *(float4*)(yp + 4) = y1;
    } else {
      y0.x = fmaxf(y0.x, 0.f); y0.y = fmaxf(y0.y, 0.f); y0.z = fmaxf(y0.z, 0.f); y0.w = fmaxf(y0.w, 0.f);
      y1.x = fmaxf(y1.x, 0.f); y1.y = fmaxf(y1.y, 0.f); y1.z = fmaxf(y1.z, 0.f); y1.w = fmaxf(y1.w, 0.f);
      if (mode == 1) {
        *(float4*)yp = y0; *(float4*)(yp + 4) = y1;
      } else {
        uint4 pk;
        pk.x = (uint)f2bf(y0.x) | ((uint)f2bf(y0.y) << 16);
        pk.y = (uint)f2bf(y0.z) | ((uint)f2bf(y0.w) << 16);
        pk.z = (uint)f2bf(y1.x) | ((uint)f2bf(y1.y) << 16);
        pk.w = (uint)f2bf(y1.z) | ((uint)f2bf(y1.w) << 16);
        *(uint4*)(xbOut + (((size_t)d) << 7) + (tx << 3)) = pk;
      }
    }
  }
}

// ---------------- launch ----------------

extern "C" void kernel_launch(void* const* d_in, const int* in_sizes, int n_in,
                              void* d_out, int out_size, void* d_ws, size_t ws_size,
                              hipStream_t stream) {
  const float* entity = (const float*)d_in[0];
  const float* comp   = (const float*)d_in[1];
  const float* basis  = (const float*)d_in[2];
  const float* root   = (const float*)d_in[3];
  const float* bias   = (const float*)d_in[4];
  const int*   eidx   = (const int*)d_in[5];
  const int*   etype  = (const int*)d_in[6];
  const int E = in_sizes[6];
  const int* src = eidx;
  const int* dst = eidx + E;

  char* ws = (char*)d_ws;
  const size_t Epad = (size_t)E + (size_t)R_ * TE;
  const int uTiles = (E + TE - 1) / TE + R_;
  const int NBLK = (N_ + 1 + 255) / 256;
  auto al = [](size_t x) { return (x + 255) & ~(size_t)255; };

  size_t o_Wpack  = 0;
  size_t o_srcdst = al(o_Wpack + (size_t)(R_ + 1) * D_ * D_ * 2);   // +1 slot for packed root
  size_t o_normS  = al(o_srcdst + Epad * 8);
  size_t o_posbuf = al(o_normS + Epad * 4);
  size_t o_degDst = al(o_posbuf + (size_t)E * 4);
  size_t o_dstOff = al(o_degDst + (size_t)N_ * 4);
  size_t o_cursD  = al(o_dstOff + (size_t)(N_ + 8) * 4);
  size_t o_bounds = al(o_cursD + (size_t)N_ * 4);
  size_t o_tileRel= al(o_bounds + (size_t)MAXC * N_ * 4);
  size_t o_small  = al(o_tileRel + (size_t)uTiles * 4);
  size_t o_y1     = al(o_small + 8192);
  size_t o_xb     = al(o_y1 + (size_t)N_ * D_ * 4);
  size_t o_msg    = al(o_xb + (size_t)N_ * D_ * 2);

  // alias inside the msg region (dead before first msg write):
  size_t o_Wf     = o_msg;                 // per-layer, dead after k_packW (before msg writes)

  ushort* Wpack  = (ushort*)(ws + o_Wpack);
  int2*   srcdst = (int2*)(ws + o_srcdst);
  float*  normS  = (float*)(ws + o_normS);
  int*    posbuf = (int*)(ws + o_posbuf);
  int*    degDst = (int*)(ws + o_degDst);
  int*    dstOff = (int*)(ws + o_dstOff);
  int*    cursD  = (int*)(ws + o_cursD);
  int*    bounds = (int*)(ws + o_bounds);
  int*    tileRel= (int*)(ws + o_tileRel);
  int*    hist   = (int*)(ws + o_small);
  int*    padOff = hist + 256;
  int*    cursor = hist + 512;
  int*    blkSum = hist + 768;
  int*    blkOff = hist + 1280;
  float*  y1     = (float*)(ws + o_y1);
  ushort* xb     = (ushort*)(ws + o_xb);
  float*  Wf     = (float*)(ws + o_Wf);
  ushort* msg    = (ushort*)(ws + o_msg);
  ushort* rootPack = Wpack + (size_t)R_ * D_ * D_;

  (void)hipMemsetAsync(ws + o_srcdst, 0xFF, Epad * 8, stream);   // padding: src=dst=-1
  (void)hipMemsetAsync(ws + o_degDst, 0, (size_t)N_ * 4, stream);
  (void)hipMemsetAsync(ws + o_small, 0, 8192, stream);

  int gH = (E + 4095) / 4096;
  k_hist<<<gH, 256, 0, stream>>>(etype, E, hist);
  k_scanRel<<<1, 256, 0, stream>>>(hist, padOff, cursor);
  k_scatter<<<gH, 256, 0, stream>>>(src, dst, etype, E, cursor, srcdst, degDst);
  k_tileRel<<<(uTiles + 255) / 256, 256, 0, stream>>>(padOff, tileRel, uTiles);
  k_degPart<<<NBLK, 256, 0, stream>>>(degDst, blkSum);
  k_scanBlk<<<1, 512, 0, stream>>>(blkSum, blkOff, NBLK);
  k_writeOff<<<NBLK, 256, 0, stream>>>(degDst, blkOff, dstOff, cursD);

  // chunking: ws capacity AND L3-residency target (~136MB per chunk -> nch=3)
  size_t cap = (ws_size > o_msg + 16384) ? (ws_size - o_msg) : (size_t)16384;
  size_t tileBytes = (size_t)TE * D_ * 2;
  long long maxT = (long long)(cap / tileBytes);
  if (maxT < 1) maxT = 1;
  int nch = (int)((uTiles + maxT - 1) / maxT);
  if (nch < 1) nch = 1;
  size_t totalMsg = (size_t)uTiles * tileBytes;
  int nchT = (int)((totalMsg + ((size_t)136 << 20) - 1) / ((size_t)136 << 20));
  if (nch < nchT) nch = nchT;
  if (nch > MAXC) nch = MAXC;
  int chunkTiles = (uTiles + nch - 1) / nch;
  nch = (uTiles + chunkTiles - 1) / chunkTiles;

  // chunk-major posbuf: scatter per chunk, snapshot cursors
  for (int c = 0; c < nch; c++) {
    int plo = c * chunkTiles * TE;
    int phi = (c + 1) * chunkTiles * TE; if (phi > uTiles * TE) phi = uTiles * TE;
    int gS = (phi - plo + 255) / 256;
    if (gS > 0)
      k_scatterDst<<<gS, 256, 0, stream>>>(srcdst, padOff, cursD, posbuf, plo, phi);
    k_copyBound<<<(N_ + 255) / 256, 256, 0, stream>>>(cursD, bounds + (size_t)c * N_);
  }

  k_norm<<<(N_ + 3) / 4, 256, 0, stream>>>(posbuf, dstOff, tileRel, normS);

  int ntR = (N_ + TE - 1) / TE;
  int gAgg = (N_ + 3) / 4;
  k_cast<<<(N_ * D_ / 8 + 255) / 256, 256, 0, stream>>>(entity, xb, N_ * D_ / 8);
  for (int l = 0; l < 2; l++) {
    float* yout = l ? (float*)d_out : y1;
    k_computeW<<<R_ * 64, 256, 0, stream>>>(comp + l * R_ * B_, basis + (size_t)l * B_ * D_ * D_, Wf);
    k_packW<<<R_, 256, 0, stream>>>(Wf, Wpack);
    k_packW<<<1, 256, 0, stream>>>(root + (size_t)l * D_ * D_, rootPack);
    k_root_mfma<<<(ntR + RG_ - 1) / RG_, 256, 0, stream>>>(xb, rootPack, bias + l * D_, yout, ntR);
    for (int c = 0; c < nch; c++) {
      int t0 = c * chunkTiles;
      int t1 = t0 + chunkTiles; if (t1 > uTiles) t1 = uTiles;
      int tiles = t1 - t0;
      int G = (tiles + 1023) / 1024; if (G < 4) G = 4;
      int gB = (tiles + G - 1) / G;
      k_edges_mfma<<<gB, 256, 0, stream>>>(xb, Wpack, srcdst, normS, tileRel, padOff, msg, t0, t1, G);
      const int* jlo = (c == 0) ? dstOff : bounds + (size_t)(c - 1) * N_;
      const int* jhi = bounds + (size_t)c * N_;
      int mode = (c == nch - 1) ? (l ? 1 : 2) : 0;
      k_agg2<<<gAgg, 256, 0, stream>>>(msg, posbuf, jlo, jhi, yout, xb, t0 * TE, mode);
    }
  }
}

// Round 12
// 973.730 us; speedup vs baseline: 1.8573x; 1.0685x over previous
//
#include <hip/hip_runtime.h>
#include <hip/hip_bf16.h>
#include <stdint.h>

#define D_ 128
#define R_ 200
#define B_ 50
#define N_ 100000
#define TE 64
#define RG_ 4
#define MAXC 8

typedef __attribute__((ext_vector_type(8))) short s8b;
typedef __attribute__((ext_vector_type(4))) float f32x4;
typedef __attribute__((ext_vector_type(4))) uint u32x4;

// ---------------- helpers ----------------

__device__ __forceinline__ ushort f2bf(float f) {   // RTN-even fp32 -> bf16
  uint u = __float_as_uint(f);
  return (ushort)((u + 0x7fffu + ((u >> 16) & 1u)) >> 16);
}
__device__ __forceinline__ float bf2f(ushort u) {
  return __uint_as_float(((uint)u) << 16);
}

// ---------------- counting / sorting machinery ----------------

__global__ __launch_bounds__(256) void k_hist(const int* __restrict__ et, int E, int* __restrict__ hist) {
  __shared__ int h[R_];
  for (int i = threadIdx.x; i < R_; i += 256) h[i] = 0;
  __syncthreads();
  int base = blockIdx.x * 4096;
  for (int j = 0; j < 16; j++) {
    int i = base + j * 256 + threadIdx.x;
    if (i < E) atomicAdd(&h[et[i]], 1);
  }
  __syncthreads();
  for (int i = threadIdx.x; i < R_; i += 256) { int v = h[i]; if (v) atomicAdd(&hist[i], v); }
}

// parallel relation scan with TE-padding (1 block, 256 threads)
__global__ __launch_bounds__(256) void k_scanRel(const int* __restrict__ hist,
                                                 int* __restrict__ padOff, int* __restrict__ cursor) {
  __shared__ int s[256];
  int tid = threadIdx.x;
  int v = (tid < R_) ? ((hist[tid] + TE - 1) / TE) * TE : 0;
  s[tid] = v;
  __syncthreads();
  for (int off = 1; off < 256; off <<= 1) {
    int t = (tid >= off) ? s[tid - off] : 0;
    __syncthreads();
    s[tid] += t;
    __syncthreads();
  }
  if (tid < R_) { int e = s[tid] - v; padOff[tid] = e; cursor[tid] = e; }
  if (tid == R_ - 1) padOff[R_] = s[tid];
}

// relation-sort scatter + per-(chunk,dst) rank/count in ONE atomic pass
__global__ __launch_bounds__(256) void k_scatter(const int* __restrict__ src, const int* __restrict__ dst,
                                                 const int* __restrict__ et, int E,
                                                 int* __restrict__ cursor,
                                                 int2* __restrict__ srcdst, int* __restrict__ rankS,
                                                 int* __restrict__ cntCD, int chunkP) {
  __shared__ int h[R_];
  __shared__ int gb[R_];
  for (int i = threadIdx.x; i < R_; i += 256) h[i] = 0;
  __syncthreads();
  int base = blockIdx.x * 4096;
  int lrank[16];
#pragma unroll
  for (int j = 0; j < 16; j++) {
    int i = base + j * 256 + threadIdx.x;
    lrank[j] = (i < E) ? atomicAdd(&h[et[i]], 1) : 0;
  }
  __syncthreads();
  for (int i = threadIdx.x; i < R_; i += 256) { int v = h[i]; gb[i] = v ? atomicAdd(&cursor[i], v) : 0; }
  __syncthreads();
#pragma unroll
  for (int j = 0; j < 16; j++) {
    int i = base + j * 256 + threadIdx.x;
    if (i < E) {
      int r = et[i], d = dst[i];
      int pos = gb[r] + lrank[j];
      int2 sd; sd.x = src[i]; sd.y = d;
      srcdst[pos] = sd;
      int c = pos / chunkP;
      rankS[pos] = atomicAdd(&cntCD[c * N_ + d], 1);
    }
  }
}

__global__ __launch_bounds__(256) void k_tileRel(const int* __restrict__ padOff, int* __restrict__ tileRel, int uT) {
  int t = blockIdx.x * 256 + threadIdx.x;
  if (t >= uT) return;
  int base = t * TE;
  if (base >= padOff[R_]) { tileRel[t] = 0; return; }
  int lo = 0, hi = R_ - 1;
  while (lo < hi) { int mid = (lo + hi + 1) >> 1; if (padOff[mid] <= base) lo = mid; else hi = mid - 1; }
  tileRel[t] = lo;
}

// ---------------- dst offsets from per-(chunk,dst) counts ----------------

__global__ __launch_bounds__(256) void k_deg(const int* __restrict__ cntCD, int* __restrict__ deg, int nch) {
  int d = blockIdx.x * 256 + threadIdx.x;
  if (d >= N_) return;
  int s = 0;
  for (int c = 0; c < nch; ++c) s += cntCD[c * N_ + d];
  deg[d] = s;
}

__global__ __launch_bounds__(256) void k_degPart(const int* __restrict__ deg, int* __restrict__ blkSum) {
  __shared__ int ws_[4];
  int i = blockIdx.x * 256 + threadIdx.x;
  int v = (i < N_) ? deg[i] : 0;
#pragma unroll
  for (int off = 32; off >= 1; off >>= 1) v += __shfl_down(v, off);
  if ((threadIdx.x & 63) == 0) ws_[threadIdx.x >> 6] = v;
  __syncthreads();
  if (threadIdx.x == 0) blkSum[blockIdx.x] = ws_[0] + ws_[1] + ws_[2] + ws_[3];
}

__global__ __launch_bounds__(512) void k_scanBlk(const int* __restrict__ blkSum, int* __restrict__ blkOff, int nblk) {
  __shared__ int s[512];
  int tid = threadIdx.x;
  int v = (tid < nblk) ? blkSum[tid] : 0;
  s[tid] = v;
  __syncthreads();
  for (int off = 1; off < 512; off <<= 1) {
    int t = (tid >= off) ? s[tid - off] : 0;
    __syncthreads();
    s[tid] += t;
    __syncthreads();
  }
  if (tid < nblk) blkOff[tid] = s[tid] - v;   // exclusive
}

__global__ __launch_bounds__(256) void k_writeOff(const int* __restrict__ deg, const int* __restrict__ blkOff,
                                                  int* __restrict__ dstOff) {
  __shared__ int s[256];
  int i = blockIdx.x * 256 + threadIdx.x;
  int tid = threadIdx.x;
  int v = (i < N_) ? deg[i] : 0;
  s[tid] = v;
  __syncthreads();
  for (int off = 1; off < 256; off <<= 1) {
    int t = (tid >= off) ? s[tid - off] : 0;
    __syncthreads();
    s[tid] += t;
    __syncthreads();
  }
  int e = blkOff[blockIdx.x] + s[tid] - v;    // global exclusive prefix
  if (i < N_) dstOff[i] = e;
  else if (i == N_) dstOff[N_] = e;
}

// base[c][d] = dstOff[d] + sum_{c'<c} cntCD[c'][d]  (chunk-major segment layout)
__global__ __launch_bounds__(256) void k_base(const int* __restrict__ cntCD, const int* __restrict__ dstOff,
                                              int* __restrict__ base, int nch) {
  int d = blockIdx.x * 256 + threadIdx.x;
  if (d >= N_) return;
  int b = dstOff[d];
  for (int c = 0; c < nch; ++c) { base[c * N_ + d] = b; b += cntCD[c * N_ + d]; }
}

// non-atomic posbuf build: chunk-major within each dst segment
__global__ __launch_bounds__(256) void k_buildPos(const int2* __restrict__ srcdst, const int* __restrict__ rankS,
                                                  const int* __restrict__ base, int* __restrict__ posbuf,
                                                  int chunkP, int pTot) {
  int p = blockIdx.x * 256 + threadIdx.x;
  if (p >= pTot) return;
  int d = srcdst[p].y;
  if (d < 0) return;                 // padding slot
  int c = p / chunkP;
  posbuf[base[c * N_ + d] + rankS[p]] = p;
}

// ---------------- per-edge mean-norm from dst-sorted segments ----------------

__global__ __launch_bounds__(256) void k_norm(const int* __restrict__ posbuf, const int* __restrict__ dstOff,
                                              const int* __restrict__ tileRel, float* __restrict__ normS) {
  __shared__ int rels[4][128];
  int d = blockIdx.x * 4 + (threadIdx.x >> 6);
  int sub = threadIdx.x >> 6;
  int l = threadIdx.x & 63;
  int s0 = 0, deg = 0;
  if (d < N_) { s0 = dstOff[d]; deg = dstOff[d + 1] - s0; }
  int cap = deg < 128 ? deg : 128;
  int myp[4]; int myr[4];
  for (int j = l, t = 0; j < cap; j += 64, ++t) {
    int p = posbuf[s0 + j];
    int r = tileRel[p >> 6];
    rels[sub][j] = r;
    if (t < 4) { myp[t] = p; myr[t] = r; }
  }
  __syncthreads();
  if (d >= N_) return;
  for (int j = l, t = 0; j < deg; j += 64, ++t) {
    int p, r;
    if (j < 128 && t < 4) { p = myp[t]; r = myr[t]; }
    else { p = posbuf[s0 + j]; r = tileRel[p >> 6]; }
    int cnt = 0;
    for (int k = 0; k < deg; k++) {
      int rk = (k < 128) ? rels[sub][k] : tileRel[posbuf[s0 + k] >> 6];
      cnt += (rk == r) ? 1 : 0;
    }
    normS[p] = 1.0f / (float)(cnt > 0 ? cnt : 1);
  }
}

// ---------------- W_r = sum_b comp[r,b]*basis[b]; pack to B-fragment order ----------------

__global__ __launch_bounds__(256) void k_computeW(const float* __restrict__ comp, const float* __restrict__ basis,
                                                  float* __restrict__ W) {
  __shared__ float c[B_];
  int r = blockIdx.x >> 6;
  int chunk = blockIdx.x & 63;
  if (threadIdx.x < B_) c[threadIdx.x] = comp[r * B_ + threadIdx.x];
  __syncthreads();
  int ij = chunk * 256 + threadIdx.x;
  float acc = 0.f;
#pragma unroll 10
  for (int b = 0; b < B_; b++) acc += c[b] * basis[b * (D_ * D_) + ij];
  W[r * (D_ * D_) + ij] = acc;
}

// pack: Wpack[r][ks][cg][lane][j] = bf16(W[r][ks*32+(lane>>4)*8+j][cg*16+(lane&15)])
__global__ __launch_bounds__(256) void k_packW(const float* __restrict__ W, ushort* __restrict__ Wpack) {
  int r = blockIdx.x;
  const float* Wr = W + (size_t)r * (D_ * D_);
  ushort* out = Wpack + (size_t)r * (D_ * D_);
  for (int i = threadIdx.x; i < D_ * D_; i += 256) {
    int j = i & 7, l = (i >> 3) & 63, cg = (i >> 9) & 7, ks = i >> 12;
    int k = ks * 32 + (l >> 4) * 8 + j;
    int n = cg * 16 + (l & 15);
    out[i] = f2bf(Wr[k * D_ + n]);
  }
}

__global__ __launch_bounds__(256) void k_cast(const float* __restrict__ x, ushort* __restrict__ xb, int n8) {
  int i = blockIdx.x * 256 + threadIdx.x;
  if (i >= n8) return;
  const float4* xp = (const float4*)(x + (size_t)i * 8);
  float4 a = xp[0], b = xp[1];
  uint4 pk;
  pk.x = (uint)f2bf(a.x) | ((uint)f2bf(a.y) << 16);
  pk.y = (uint)f2bf(a.z) | ((uint)f2bf(a.w) << 16);
  pk.z = (uint)f2bf(b.x) | ((uint)f2bf(b.y) << 16);
  pk.w = (uint)f2bf(b.z) | ((uint)f2bf(b.w) << 16);
  *(uint4*)(xb + (size_t)i * 8) = pk;
}

// ---------------- y = x @ root + bias (MFMA, LDS-resident W, full-line stores) ----------------

__global__ __launch_bounds__(256, 2) void k_root_mfma(
    const ushort* __restrict__ xb, const ushort* __restrict__ rootPack,
    const float* __restrict__ bias, float* __restrict__ y, int nt) {
  __shared__ ushort Wl[D_ * D_];        // 32 KB
  __shared__ float stg[4][16 * 132];    // 33.8 KB, wave-private fp32 staging
  int tstart = blockIdx.x * RG_;
  if (tstart >= nt) return;
  int tend = tstart + RG_; if (tend > nt) tend = nt;
  int w = threadIdx.x >> 6, l = threadIdx.x & 63;
  int q = l >> 4, tx = l & 15;
  int half = l >> 5, l32 = l & 31;
  float* st = stg[w];
  {
    const uint4* wp = (const uint4*)rootPack;
    uint4* wl = (uint4*)Wl;
#pragma unroll
    for (int i = 0; i < 8; ++i) wl[i * 256 + threadIdx.x] = wp[i * 256 + threadIdx.x];
  }
  float bv[8];
#pragma unroll
  for (int cg = 0; cg < 8; ++cg) bv[cg] = bias[cg * 16 + tx];
  s8b a0, a1, a2, a3;
  {
    int gr = tstart * TE + 16 * w + tx; if (gr >= N_) gr = N_ - 1;
    const s8b* xr = (const s8b*)(xb + (size_t)gr * D_);
    a0 = xr[q]; a1 = xr[4 + q]; a2 = xr[8 + q]; a3 = xr[12 + q];
  }
  __syncthreads();
  for (int tile = tstart; tile < tend; ++tile) {
    int base = tile * TE;
    s8b n0, n1, n2, n3;
    bool pre = (tile + 1 < tend);
    if (pre) {
      int gr = base + TE + 16 * w + tx; if (gr >= N_) gr = N_ - 1;
      const s8b* xn = (const s8b*)(xb + (size_t)gr * D_);
      n0 = xn[q]; n1 = xn[4 + q]; n2 = xn[8 + q]; n3 = xn[12 + q];
    }
    f32x4 acc[8];
#pragma unroll
    for (int cg = 0; cg < 8; ++cg) acc[cg] = (f32x4){0.f, 0.f, 0.f, 0.f};
#pragma unroll
    for (int cg = 0; cg < 8; ++cg) {
      s8b b0 = *(const s8b*)&Wl[((0 * 8 + cg) * 64 + l) * 8];
      s8b b1 = *(const s8b*)&Wl[((1 * 8 + cg) * 64 + l) * 8];
      s8b b2 = *(const s8b*)&Wl[((2 * 8 + cg) * 64 + l) * 8];
      s8b b3 = *(const s8b*)&Wl[((3 * 8 + cg) * 64 + l) * 8];
      acc[cg] = __builtin_amdgcn_mfma_f32_16x16x32_bf16(a0, b0, acc[cg], 0, 0, 0);
      acc[cg] = __builtin_amdgcn_mfma_f32_16x16x32_bf16(a1, b1, acc[cg], 0, 0, 0);
      acc[cg] = __builtin_amdgcn_mfma_f32_16x16x32_bf16(a2, b2, acc[cg], 0, 0, 0);
      acc[cg] = __builtin_amdgcn_mfma_f32_16x16x32_bf16(a3, b3, acc[cg], 0, 0, 0);
    }
    // stage to wave-private LDS (fp32, no barrier)
#pragma unroll
    for (int cg = 0; cg < 8; ++cg)
#pragma unroll
      for (int r = 0; r < 4; ++r)
        st[(4 * q + r) * 132 + cg * 16 + tx] = acc[cg][r] + bv[cg];
    // write back: each instr = 2 rows x 512B contiguous = full 128B lines
    int grBase = base + 16 * w;
#pragma unroll
    for (int k = 0; k < 8; ++k) {
      int row = 2 * k + half;
      int gr = grBase + row;
      f32x4 v = *(const f32x4*)&st[row * 132 + l32 * 4];
      if (gr < N_) *(f32x4*)(y + (size_t)gr * D_ + l32 * 4) = v;
    }
    if (pre) { a0 = n0; a1 = n1; a2 = n2; a3 = n3; }
  }
}

// ---------------- phase A: MFMA edge messages ----------------
// LDS-resident W + wave-private staging tile for full-128B-line msg stores.

__global__ __launch_bounds__(256, 4) void k_edges_mfma(
    const ushort* __restrict__ xb, const ushort* __restrict__ Wpack,
    const int2* __restrict__ srcdst, const float* __restrict__ normS,
    const int* __restrict__ tileRel, const int* __restrict__ padOff,
    ushort* __restrict__ msg, int tile0, int tile1, int G) {
  __shared__ ushort Wl[D_ * D_];        // 32 KB, one relation
  __shared__ ushort stg[4][16 * 136];   // 17 KB, wave-private staging (pad 136)
  int padTot = padOff[R_];
  int w = threadIdx.x >> 6, l = threadIdx.x & 63;
  int q = l >> 4, tx = l & 15;
  int g = l >> 3, m = l & 7;
  ushort* st = stg[w];
  int curRel = -1;
  for (int tb = tile0 + blockIdx.x * G; tb < tile1; tb += gridDim.x * G) {
    if (tb * TE >= padTot) break;
    int tend = tb + G; if (tend > tile1) tend = tile1;
    s8b a0, a1, a2, a3;
    {
      int2 sd = srcdst[tb * TE + 16 * w + tx];
      int sr = sd.x < 0 ? 0 : sd.x;
      const s8b* xr = (const s8b*)(xb + (size_t)sr * D_);
      a0 = xr[q]; a1 = xr[4 + q]; a2 = xr[8 + q]; a3 = xr[12 + q];
    }
    for (int tile = tb; tile < tend; ++tile) {
      int base = tile * TE;
      if (base >= padTot) break;
      int rel = tileRel[tile];
      if (rel != curRel) {                    // block-uniform branch
        curRel = rel;
        __syncthreads();
        const uint4* wp = (const uint4*)(Wpack + (size_t)rel * (D_ * D_));
        uint4* wl = (uint4*)Wl;
#pragma unroll
        for (int i = 0; i < 8; ++i) wl[i * 256 + threadIdx.x] = wp[i * 256 + threadIdx.x];
        __syncthreads();
      }
      float nv[4];
#pragma unroll
      for (int r = 0; r < 4; ++r) nv[r] = normS[base + 16 * w + 4 * q + r];
      // prefetch next tile's A fragments
      s8b n0, n1, n2, n3;
      int nb = base + TE;
      bool pre = (tile + 1 < tend) && (nb < padTot);
      if (pre) {
        int2 sd = srcdst[nb + 16 * w + tx];
        int sr = sd.x < 0 ? 0 : sd.x;
        const s8b* xn = (const s8b*)(xb + (size_t)sr * D_);
        n0 = xn[q]; n1 = xn[4 + q]; n2 = xn[8 + q]; n3 = xn[12 + q];
      }
      f32x4 acc[8];
#pragma unroll
      for (int cg = 0; cg < 8; ++cg) acc[cg] = (f32x4){0.f, 0.f, 0.f, 0.f};
#pragma unroll
      for (int cg = 0; cg < 8; ++cg) {
        s8b b0 = *(const s8b*)&Wl[((0 * 8 + cg) * 64 + l) * 8];
        s8b b1 = *(const s8b*)&Wl[((1 * 8 + cg) * 64 + l) * 8];
        s8b b2 = *(const s8b*)&Wl[((2 * 8 + cg) * 64 + l) * 8];
        s8b b3 = *(const s8b*)&Wl[((3 * 8 + cg) * 64 + l) * 8];
        acc[cg] = __builtin_amdgcn_mfma_f32_16x16x32_bf16(a0, b0, acc[cg], 0, 0, 0);
        acc[cg] = __builtin_amdgcn_mfma_f32_16x16x32_bf16(a1, b1, acc[cg], 0, 0, 0);
        acc[cg] = __builtin_amdgcn_mfma_f32_16x16x32_bf16(a2, b2, acc[cg], 0, 0, 0);
        acc[cg] = __builtin_amdgcn_mfma_f32_16x16x32_bf16(a3, b3, acc[cg], 0, 0, 0);
      }
      // stage to wave-private LDS (no barrier; in-wave lgkmcnt ordering)
#pragma unroll
      for (int cg = 0; cg < 8; ++cg)
#pragma unroll
        for (int r = 0; r < 4; ++r)
          st[(4 * q + r) * 136 + cg * 16 + tx] = f2bf(acc[cg][r] * nv[r]);
      // write back as full 128B lines: 4 instrs, each 8 rows x 128B aligned
      ushort* mbase = msg + (size_t)(base - tile0 * TE + 16 * w) * D_;
#pragma unroll
      for (int jj = 0; jj < 2; ++jj)
#pragma unroll
        for (int hh = 0; hh < 2; ++hh) {
          int row = 8 * jj + g;
          u32x4 v = *(const u32x4*)&st[row * 136 + hh * 64 + m * 8];
          *(u32x4*)(mbase + (size_t)row * D_ + hh * 64 + m * 8) = v;
        }
      if (pre) { a0 = n0; a1 = n1; a2 = n2; a3 = n3; }
    }
  }
}

// ---------------- phase B: wave-per-dst aggregation ----------------
// mode 0: RMW fp32 y.  mode 1: final layer-2 (relu, fp32 y).  mode 2: final layer-1 (relu, write bf16 xb).

__global__ __launch_bounds__(256) void k_agg2(const ushort* __restrict__ msg, const int* __restrict__ posbuf,
                                              const int* __restrict__ jlo, const int* __restrict__ jhi,
                                              float* __restrict__ y, ushort* __restrict__ xbOut,
                                              int plo, int mode) {
  int d = blockIdx.x * 4 + (threadIdx.x >> 6);
  if (d >= N_) return;
  int l = threadIdx.x & 63, sub = l >> 4, tx = l & 15;
  int s0 = jlo[d], s1 = jhi[d];
  float acc[8];
#pragma unroll
  for (int i = 0; i < 8; ++i) acc[i] = 0.f;
  for (int j = s0 + sub; j < s1; j += 4) {
    int p = posbuf[j];
    u32x4 mv = *(const u32x4*)(msg + (((size_t)(p - plo)) << 7) + (tx << 3));
    acc[0] += bf2f((ushort)mv[0]); acc[1] += bf2f((ushort)(mv[0] >> 16));
    acc[2] += bf2f((ushort)mv[1]); acc[3] += bf2f((ushort)(mv[1] >> 16));
    acc[4] += bf2f((ushort)mv[2]); acc[5] += bf2f((ushort)(mv[2] >> 16));
    acc[6] += bf2f((ushort)mv[3]); acc[7] += bf2f((ushort)(mv[3] >> 16));
  }
#pragma unroll
  for (int i = 0; i < 8; ++i) {
    acc[i] += __shfl_xor(acc[i], 16);
    acc[i] += __shfl_xor(acc[i], 32);
  }
  if (sub == 0) {
    float* yp = y + (((size_t)d) << 7) + (tx << 3);
    float4 y0 = *(float4*)yp, y1 = *(float4*)(yp + 4);
    y0.x += acc[0]; y0.y += acc[1]; y0.z += acc[2]; y0.w += acc[3];
    y1.x += acc[4]; y1.y += acc[5]; y1.z += acc[6]; y1.w += acc[7];
    if (mode == 0) {
      *(float4*)yp = y0; *(float4*)(yp + 4) = y1;
    } else {
      y0.x = fmaxf(y0.x, 0.f); y0.y = fmaxf(y0.y, 0.f); y0.z = fmaxf(y0.z, 0.f); y0.w = fmaxf(y0.w, 0.f);
      y1.x = fmaxf(y1.x, 0.f); y1.y = fmaxf(y1.y, 0.f); y1.z = fmaxf(y1.z, 0.f); y1.w = fmaxf(y1.w, 0.f);
      if (mode == 1) {
        *(float4*)yp = y0; *(float4*)(yp + 4) = y1;
      } else {
        uint4 pk;
        pk.x = (uint)f2bf(y0.x) | ((uint)f2bf(y0.y) << 16);
        pk.y = (uint)f2bf(y0.z) | ((uint)f2bf(y0.w) << 16);
        pk.z = (uint)f2bf(y1.x) | ((uint)f2bf(y1.y) << 16);
        pk.w = (uint)f2bf(y1.z) | ((uint)f2bf(y1.w) << 16);
        *(uint4*)(xbOut + (((size_t)d) << 7) + (tx << 3)) = pk;
      }
    }
  }
}

// ---------------- launch ----------------

extern "C" void kernel_launch(void* const* d_in, const int* in_sizes, int n_in,
                              void* d_out, int out_size, void* d_ws, size_t ws_size,
                              hipStream_t stream) {
  const float* entity = (const float*)d_in[0];
  const float* comp   = (const float*)d_in[1];
  const float* basis  = (const float*)d_in[2];
  const float* root   = (const float*)d_in[3];
  const float* bias   = (const float*)d_in[4];
  const int*   eidx   = (const int*)d_in[5];
  const int*   etype  = (const int*)d_in[6];
  const int E = in_sizes[6];
  const int* src = eidx;
  const int* dst = eidx + E;

  char* ws = (char*)d_ws;
  const size_t Epad = (size_t)E + (size_t)R_ * TE;
  const int uTiles = (E + TE - 1) / TE + R_;
  const int NBLK = (N_ + 1 + 255) / 256;
  auto al = [](size_t x) { return (x + 255) & ~(size_t)255; };

  size_t o_Wpack  = 0;
  size_t o_srcdst = al(o_Wpack + (size_t)(R_ + 1) * D_ * D_ * 2);   // +1 slot for packed root
  size_t o_normS  = al(o_srcdst + Epad * 8);
  size_t o_posbuf = al(o_normS + Epad * 4);
  size_t o_rankS  = al(o_posbuf + (size_t)E * 4);
  size_t o_degDst = al(o_rankS + Epad * 4);
  size_t o_dstOff = al(o_degDst + (size_t)N_ * 4);
  size_t o_base   = al(o_dstOff + (size_t)(N_ + 8) * 4);
  size_t o_cntCD  = al(o_base + (size_t)MAXC * N_ * 4);
  size_t o_tileRel= al(o_cntCD + (size_t)MAXC * N_ * 4);
  size_t o_small  = al(o_tileRel + (size_t)uTiles * 4);
  size_t o_y1     = al(o_small + 8192);
  size_t o_xb     = al(o_y1 + (size_t)N_ * D_ * 4);
  size_t o_msg    = al(o_xb + (size_t)N_ * D_ * 2);

  // alias inside the msg region (dead before first msg write):
  size_t o_Wf     = o_msg;                 // per-layer, dead after k_packW (before msg writes)

  ushort* Wpack  = (ushort*)(ws + o_Wpack);
  int2*   srcdst = (int2*)(ws + o_srcdst);
  float*  normS  = (float*)(ws + o_normS);
  int*    posbuf = (int*)(ws + o_posbuf);
  int*    rankS  = (int*)(ws + o_rankS);
  int*    degDst = (int*)(ws + o_degDst);
  int*    dstOff = (int*)(ws + o_dstOff);
  int*    base_  = (int*)(ws + o_base);
  int*    cntCD  = (int*)(ws + o_cntCD);
  int*    tileRel= (int*)(ws + o_tileRel);
  int*    hist   = (int*)(ws + o_small);
  int*    padOff = hist + 256;
  int*    cursor = hist + 512;
  int*    blkSum = hist + 768;
  int*    blkOff = hist + 1280;
  float*  y1     = (float*)(ws + o_y1);
  ushort* xb     = (ushort*)(ws + o_xb);
  float*  Wf     = (float*)(ws + o_Wf);
  ushort* msg    = (ushort*)(ws + o_msg);
  ushort* rootPack = Wpack + (size_t)R_ * D_ * D_;

  // chunking: ws capacity AND L3-residency target (~136MB per chunk -> nch=3)
  size_t cap = (ws_size > o_msg + 16384) ? (ws_size - o_msg) : (size_t)16384;
  size_t tileBytes = (size_t)TE * D_ * 2;
  long long maxT = (long long)(cap / tileBytes);
  if (maxT < 1) maxT = 1;
  int nch = (int)((uTiles + maxT - 1) / maxT);
  if (nch < 1) nch = 1;
  size_t totalMsg = (size_t)uTiles * tileBytes;
  int nchT = (int)((totalMsg + ((size_t)136 << 20) - 1) / ((size_t)136 << 20));
  if (nch < nchT) nch = nchT;
  if (nch > MAXC) nch = MAXC;
  int chunkTiles = (uTiles + nch - 1) / nch;
  nch = (uTiles + chunkTiles - 1) / chunkTiles;
  int chunkP = chunkTiles * TE;

  (void)hipMemsetAsync(ws + o_srcdst, 0xFF, Epad * 8, stream);   // padding: src=dst=-1
  (void)hipMemsetAsync(ws + o_cntCD, 0, (size_t)MAXC * N_ * 4, stream);
  (void)hipMemsetAsync(ws + o_small, 0, 8192, stream);

  int gH = (E + 4095) / 4096;
  k_hist<<<gH, 256, 0, stream>>>(etype, E, hist);
  k_scanRel<<<1, 256, 0, stream>>>(hist, padOff, cursor);
  k_scatter<<<gH, 256, 0, stream>>>(src, dst, etype, E, cursor, srcdst, rankS, cntCD, chunkP);
  k_tileRel<<<(uTiles + 255) / 256, 256, 0, stream>>>(padOff, tileRel, uTiles);
  k_deg<<<(N_ + 255) / 256, 256, 0, stream>>>(cntCD, degDst, nch);
  k_degPart<<<NBLK, 256, 0, stream>>>(degDst, blkSum);
  k_scanBlk<<<1, 512, 0, stream>>>(blkSum, blkOff, NBLK);
  k_writeOff<<<NBLK, 256, 0, stream>>>(degDst, blkOff, dstOff);
  k_base<<<(N_ + 255) / 256, 256, 0, stream>>>(cntCD, dstOff, base_, nch);
  k_buildPos<<<(uTiles * TE + 255) / 256, 256, 0, stream>>>(srcdst, rankS, base_, posbuf, chunkP, uTiles * TE);
  k_norm<<<(N_ + 3) / 4, 256, 0, stream>>>(posbuf, dstOff, tileRel, normS);

  int ntR = (N_ + TE - 1) / TE;
  int gAgg = (N_ + 3) / 4;
  k_cast<<<(N_ * D_ / 8 + 255) / 256, 256, 0, stream>>>(entity, xb, N_ * D_ / 8);
  for (int l = 0; l < 2; l++) {
    float* yout = l ? (float*)d_out : y1;
    k_computeW<<<R_ * 64, 256, 0, stream>>>(comp + l * R_ * B_, basis + (size_t)l * B_ * D_ * D_, Wf);
    k_packW<<<R_, 256, 0, stream>>>(Wf, Wpack);
    k_packW<<<1, 256, 0, stream>>>(root + (size_t)l * D_ * D_, rootPack);
    k_root_mfma<<<(ntR + RG_ - 1) / RG_, 256, 0, stream>>>(xb, rootPack, bias + l * D_, yout, ntR);
    for (int c = 0; c < nch; c++) {
      int t0 = c * chunkTiles;
      int t1 = t0 + chunkTiles; if (t1 > uTiles) t1 = uTiles;
      int tiles = t1 - t0;
      int G = (tiles + 1023) / 1024; if (G < 4) G = 4;
      int gB = (tiles + G - 1) / G;
      k_edges_mfma<<<gB, 256, 0, stream>>>(xb, Wpack, srcdst, normS, tileRel, padOff, msg, t0, t1, G);
      const int* jlo = base_ + (size_t)c * N_;
      const int* jhi = (c == nch - 1) ? (dstOff + 1) : (base_ + (size_t)(c + 1) * N_);
      int mode = (c == nch - 1) ? (l ? 1 : 2) : 0;
      k_agg2<<<gAgg, 256, 0, stream>>>(msg, posbuf, jlo, jhi, yout, xb, t0 * TE, mode);
    }
  }
}